// Round 1
// baseline (3151.930 us; speedup 1.0000x reference)
//
#include <hip/hip_runtime.h>
#include <cmath>

#define NB 32
#define NN 1024
#define NC 64
#define NE 16

__device__ __forceinline__ float sigm(float v) { return 1.0f / (1.0f + expf(-v)); }
__device__ __forceinline__ float lrelu(float v) { return v > 0.0f ? v : 0.01f * v; }

// ---------------- Kernel 1: nv = tanh(tanh(tanh(emb0*filt)*f1)*f2) ----------------
__global__ __launch_bounds__(256) void nv_kernel(
    const float* __restrict__ x, const float* __restrict__ emb0,
    const float* __restrict__ speed, const float* __restrict__ occupy,
    const float* __restrict__ fw1, const float* __restrict__ fb1,
    const float* __restrict__ fw2, const float* __restrict__ fb2,
    const float* __restrict__ fw3, const float* __restrict__ fb3,
    const float* __restrict__ gw1, const float* __restrict__ gb1,
    const float* __restrict__ gw2, const float* __restrict__ gb2,
    const float* __restrict__ gw3, const float* __restrict__ gb3,
    float* __restrict__ nv_out)
{
    const int sub = threadIdx.x >> 6;
    const int lt = threadIdx.x & 63;
    const int row = blockIdx.x * 4 + sub;   // b*N + n

    __shared__ float xr[4][64];
    __shared__ float h1[4][16];
    __shared__ float h2[4][2];
    __shared__ float g1[4][16];
    __shared__ float g2a[4][2];
    __shared__ float g2b[4][2];
    __shared__ float f1s[4][16];

    xr[sub][lt] = x[(size_t)row * 64 + lt];
    if (lt < 16) g1[sub][lt] = sigm(speed[row] * gw1[lt] + gb1[lt]);
    __syncthreads();
    if (lt < 16) {
        float s = fb1[lt];
        #pragma unroll
        for (int i = 0; i < 64; ++i) s += xr[sub][i] * fw1[lt * 64 + i];
        h1[sub][lt] = sigm(s);
    }
    __syncthreads();
    if (lt < 2) {
        float s = fb2[lt];
        #pragma unroll
        for (int i = 0; i < 16; ++i) s += h1[sub][i] * fw2[lt * 16 + i];
        h2[sub][lt] = sigm(s);
        float s2 = gb2[lt];
        #pragma unroll
        for (int i = 0; i < 16; ++i) s2 += g1[sub][i] * gw2[lt * 16 + i];
        g2a[sub][lt] = sigm(s2);
    }
    __syncthreads();
    if (lt < 16) {
        f1s[sub][lt] = g2a[sub][0] * gw3[lt * 2] + g2a[sub][1] * gw3[lt * 2 + 1] + gb3[lt];
        g1[sub][lt] = sigm(occupy[row] * gw1[lt] + gb1[lt]);   // reuse g1 for occupy path
    }
    __syncthreads();
    if (lt < 2) {
        float s2 = gb2[lt];
        #pragma unroll
        for (int i = 0; i < 16; ++i) s2 += g1[sub][i] * gw2[lt * 16 + i];
        g2b[sub][lt] = sigm(s2);
    }
    __syncthreads();
    if (lt < 16) {
        float f2 = g2b[sub][0] * gw3[lt * 2] + g2b[sub][1] * gw3[lt * 2 + 1] + gb3[lt];
        float filt = h2[sub][0] * fw3[lt * 2] + h2[sub][1] * fw3[lt * 2 + 1] + fb3[lt];
        float v = tanhf(emb0[(size_t)row * 16 + lt] * filt);
        v = tanhf(v * f1s[sub][lt]);
        v = tanhf(v * f2);
        nv_out[(size_t)row * 16 + lt] = v;
    }
}

// ------- Kernel 2: y = LeakyReLU(S x) with S-tile = relu(nv nv^T) recomputed on the fly -------
// S is symmetric, so the same kernel serves forward and backward diffusion.
// Block: 256 threads, M-tile 64, full C=64. Thread = (tx: 4 cols, ty: 4 rows).
__global__ __launch_bounds__(256) void diffuse_kernel(
    const float* __restrict__ nv, const float* __restrict__ xin,
    float* __restrict__ yout)
{
    const int b = blockIdx.y;
    const int m0 = blockIdx.x * 64;
    const int t = threadIdx.x;
    const int lane = t & 63;
    const int w = t >> 6;
    const int tx = t & 15;
    const int ty = t >> 4;

    __shared__ float nvn[64][16];
    __shared__ float st[64][64];   // st[n][m]  (transposed so MM reads are conflict-free)
    __shared__ float xt[64][64];   // xt[n][c]

    // nv row for m = m0 + lane, kept in registers for the whole kernel
    float4 nvr[4];
    {
        const float4* p = reinterpret_cast<const float4*>(nv + ((size_t)b * NN + m0 + lane) * NE);
        nvr[0] = p[0]; nvr[1] = p[1]; nvr[2] = p[2]; nvr[3] = p[3];
    }
    float acc[4][4];
    #pragma unroll
    for (int i = 0; i < 4; ++i)
        #pragma unroll
        for (int j = 0; j < 4; ++j) acc[i][j] = 0.0f;

    const float4* nvb = reinterpret_cast<const float4*>(nv + (size_t)b * NN * NE);
    const float4* xb4 = reinterpret_cast<const float4*>(xin + (size_t)b * NN * NC);

    for (int n0 = 0; n0 < NN; n0 += 64) {
        __syncthreads();
        // stage nv tile (1024 floats) and x tile (4096 floats), both contiguous
        reinterpret_cast<float4*>(&nvn[0][0])[t] = nvb[n0 * 4 + t];
        {
            float4* xd = reinterpret_cast<float4*>(&xt[0][0]);
            const float4* xs = xb4 + n0 * 16;
            #pragma unroll
            for (int r = 0; r < 4; ++r) xd[t + 256 * r] = xs[t + 256 * r];
        }
        __syncthreads();

        // S tile: thread computes st[n][lane] for n = w*16+j (wave-uniform nvn row -> LDS broadcast)
        #pragma unroll
        for (int j = 0; j < 16; ++j) {
            int n = w * 16 + j;
            const float4* q = reinterpret_cast<const float4*>(&nvn[n][0]);
            float4 q0 = q[0], q1 = q[1], q2 = q[2], q3 = q[3];
            float s = nvr[0].x * q0.x + nvr[0].y * q0.y + nvr[0].z * q0.z + nvr[0].w * q0.w
                    + nvr[1].x * q1.x + nvr[1].y * q1.y + nvr[1].z * q1.z + nvr[1].w * q1.w
                    + nvr[2].x * q2.x + nvr[2].y * q2.y + nvr[2].z * q2.z + nvr[2].w * q2.w
                    + nvr[3].x * q3.x + nvr[3].y * q3.y + nvr[3].z * q3.z + nvr[3].w * q3.w;
            st[n][lane] = fmaxf(s, 0.0f);
        }
        __syncthreads();

        // MM: acc[i][j] += S[m0+ty*4+i][n0+n] * x[n0+n][tx*4+j]
        #pragma unroll
        for (int n = 0; n < 64; ++n) {
            float4 sv = reinterpret_cast<const float4*>(&st[n][0])[ty];
            float4 xv = reinterpret_cast<const float4*>(&xt[n][0])[tx];
            acc[0][0] += sv.x * xv.x; acc[0][1] += sv.x * xv.y; acc[0][2] += sv.x * xv.z; acc[0][3] += sv.x * xv.w;
            acc[1][0] += sv.y * xv.x; acc[1][1] += sv.y * xv.y; acc[1][2] += sv.y * xv.z; acc[1][3] += sv.y * xv.w;
            acc[2][0] += sv.z * xv.x; acc[2][1] += sv.z * xv.y; acc[2][2] += sv.z * xv.z; acc[2][3] += sv.z * xv.w;
            acc[3][0] += sv.w * xv.x; acc[3][1] += sv.w * xv.y; acc[3][2] += sv.w * xv.z; acc[3][3] += sv.w * xv.w;
        }
    }

    #pragma unroll
    for (int i = 0; i < 4; ++i) {
        float4 v;
        v.x = lrelu(acc[i][0]); v.y = lrelu(acc[i][1]); v.z = lrelu(acc[i][2]); v.w = lrelu(acc[i][3]);
        reinterpret_cast<float4*>(yout + ((size_t)b * NN + m0 + ty * 4 + i) * NC)[tx] = v;
    }
}

// ------- Kernel 3: attention pool for both xg1 and xg2 (grid.y selects triplet) -------
__global__ __launch_bounds__(256) void attnpool_kernel(
    const float* __restrict__ a0, const float* __restrict__ a1, const float* __restrict__ a2,
    const float* __restrict__ c0, const float* __restrict__ c1, const float* __restrict__ c2,
    const float* __restrict__ att_w, const float* __restrict__ att_b,
    const float* __restrict__ w1, float* __restrict__ gf_out)
{
    const int b = blockIdx.x;
    const int which = blockIdx.y;
    const float* p0 = which ? c0 : a0;
    const float* p1 = which ? c1 : a1;
    const float* p2 = which ? c2 : a2;
    const int t = threadIdx.x;
    const int lane = t & 63;
    const int w = t >> 6;

    __shared__ float sc[NN];
    __shared__ float red[4];
    __shared__ float gfp[4][64];
    __shared__ float gfin[64];

    const float aw = att_w[lane];
    const size_t base = (size_t)b * NN * NC;

    // scores
    for (int n = w; n < NN; n += 4) {
        size_t idx = base + (size_t)n * NC + lane;
        float nf = (p0[idx] + p1[idx] + p2[idx]) * (1.0f / 3.0f);
        float v = nf * aw;
        #pragma unroll
        for (int off = 32; off > 0; off >>= 1) v += __shfl_xor(v, off);
        if (lane == 0) sc[n] = v + att_b[0];
    }
    __syncthreads();
    // softmax over nodes
    float m = -INFINITY;
    for (int i = t; i < NN; i += 256) m = fmaxf(m, sc[i]);
    #pragma unroll
    for (int off = 32; off > 0; off >>= 1) m = fmaxf(m, __shfl_xor(m, off));
    if (lane == 0) red[w] = m;
    __syncthreads();
    m = fmaxf(fmaxf(red[0], red[1]), fmaxf(red[2], red[3]));
    __syncthreads();
    float s = 0.0f;
    for (int i = t; i < NN; i += 256) { float e = expf(sc[i] - m); sc[i] = e; s += e; }
    #pragma unroll
    for (int off = 32; off > 0; off >>= 1) s += __shfl_xor(s, off);
    if (lane == 0) red[w] = s;
    __syncthreads();
    const float inv_denom = 1.0f / (red[0] + red[1] + red[2] + red[3]);

    // gf[c] = sum_n nf[n][c] * aw[n]
    float acc = 0.0f;
    for (int n = w; n < NN; n += 4) {
        size_t idx = base + (size_t)n * NC + lane;
        float nf = (p0[idx] + p1[idx] + p2[idx]) * (1.0f / 3.0f);
        acc += nf * sc[n];
    }
    gfp[w][lane] = acc;
    __syncthreads();
    if (w == 0) gfin[lane] = (gfp[0][lane] + gfp[1][lane] + gfp[2][lane] + gfp[3][lane]) * inv_denom;
    __syncthreads();
    if (w == 0) {
        float s2 = 0.0f;
        #pragma unroll
        for (int c = 0; c < 64; ++c) s2 += gfin[c] * w1[c * 64 + lane];
        gf_out[((size_t)which * NB + b) * 64 + lane] = s2;
    }
}

// ------- Kernel 4: per-node W = emb1[n]·pool, then d1/d2 dots + bias + gf, write out -------
__global__ __launch_bounds__(256) void final_kernel(
    const float* __restrict__ emb1,
    const float* __restrict__ wpf, const float* __restrict__ wpb,
    const float* __restrict__ bias_pool,
    const float* __restrict__ x, const float* __restrict__ xs1, const float* __restrict__ xs2,
    const float* __restrict__ xb1, const float* __restrict__ xb2,
    const float* __restrict__ gf, const float* __restrict__ alpha, const float* __restrict__ beta,
    float* __restrict__ out)
{
    const int n = blockIdx.x;
    const int t = threadIdx.x;
    const int o = t & 63;
    const int bg = t >> 6;

    __shared__ float Wk[64][64];
    __shared__ float xk[32][64];
    __shared__ float e1[16];
    if (t < 16) e1[t] = emb1[n * 16 + t];

    float acc[2][8];
    #pragma unroll
    for (int d = 0; d < 2; ++d)
        #pragma unroll
        for (int j = 0; j < 8; ++j) acc[d][j] = 0.0f;

    const float* srcs[2][3] = {{x, xs1, xs2}, {xs2, xb1, xb2}};

    #pragma unroll
    for (int dir = 0; dir < 2; ++dir) {
        const float* wp = dir ? wpb : wpf;
        #pragma unroll
        for (int k = 0; k < 3; ++k) {
            __syncthreads();   // protect Wk/xk reuse; also orders e1 before first use
            for (int idx = t; idx < 4096; idx += 256) {
                int i = idx >> 6, oo = idx & 63;
                float s = 0.0f;
                #pragma unroll
                for (int e = 0; e < 16; ++e) s += e1[e] * wp[(((size_t)e * 3 + k) * 64 + i) * 64 + oo];
                Wk[i][oo] = s;
            }
            const float* src = srcs[dir][k];
            for (int idx = t; idx < 2048; idx += 256) {
                int bb = idx >> 6, ii = idx & 63;
                xk[bb][ii] = src[((size_t)bb * NN + n) * NC + ii];
            }
            __syncthreads();
            #pragma unroll
            for (int j = 0; j < 8; ++j) {
                int bb = bg * 8 + j;
                float s = 0.0f;
                #pragma unroll
                for (int i = 0; i < 64; i += 4) {
                    float4 xv = *reinterpret_cast<const float4*>(&xk[bb][i]);
                    s += xv.x * Wk[i][o] + xv.y * Wk[i + 1][o] + xv.z * Wk[i + 2][o] + xv.w * Wk[i + 3][o];
                }
                acc[dir][j] += s;
            }
        }
    }

    float bias_o = 0.0f;
    #pragma unroll
    for (int e = 0; e < 16; ++e) bias_o += e1[e] * bias_pool[e * 64 + o];
    const float al = alpha[0], be = beta[0];
    #pragma unroll
    for (int j = 0; j < 8; ++j) {
        int bb = bg * 8 + j;
        float g = gf[(size_t)bb * 64 + o] + gf[((size_t)NB + bb) * 64 + o];
        out[((size_t)bb * NN + n) * NC + o] = al * acc[0][j] + be * acc[1][j] + bias_o + g;
    }
}

extern "C" void kernel_launch(void* const* d_in, const int* in_sizes, int n_in,
                              void* d_out, int out_size, void* d_ws, size_t ws_size,
                              hipStream_t stream)
{
    const float* x      = (const float*)d_in[0];
    const float* emb0   = (const float*)d_in[1];
    const float* emb1   = (const float*)d_in[2];
    const float* speed  = (const float*)d_in[5];
    const float* occupy = (const float*)d_in[6];
    const float* fw1 = (const float*)d_in[7];
    const float* fb1 = (const float*)d_in[8];
    const float* fw2 = (const float*)d_in[9];
    const float* fb2 = (const float*)d_in[10];
    const float* fw3 = (const float*)d_in[11];
    const float* fb3 = (const float*)d_in[12];
    const float* gw1 = (const float*)d_in[13];
    const float* gb1 = (const float*)d_in[14];
    const float* gw2 = (const float*)d_in[15];
    const float* gb2 = (const float*)d_in[16];
    const float* gw3 = (const float*)d_in[17];
    const float* gb3 = (const float*)d_in[18];
    const float* alpha = (const float*)d_in[19];
    const float* beta  = (const float*)d_in[20];
    const float* wpf = (const float*)d_in[21];
    const float* wpb = (const float*)d_in[22];
    const float* bias_pool = (const float*)d_in[23];
    const float* w1 = (const float*)d_in[24];
    const float* att_w = (const float*)d_in[25];
    const float* att_b = (const float*)d_in[26];
    float* out = (float*)d_out;

    float* ws = (float*)d_ws;
    float* nv  = ws;                                   // B*N*E
    float* xs1 = nv + (size_t)NB * NN * NE;            // B*N*C each
    float* xs2 = xs1 + (size_t)NB * NN * NC;
    float* xb1 = xs2 + (size_t)NB * NN * NC;
    float* xb2 = xb1 + (size_t)NB * NN * NC;
    float* gfb = xb2 + (size_t)NB * NN * NC;           // [2][B][64]

    hipLaunchKernelGGL(nv_kernel, dim3(NB * NN / 4), dim3(256), 0, stream,
                       x, emb0, speed, occupy, fw1, fb1, fw2, fb2, fw3, fb3,
                       gw1, gb1, gw2, gb2, gw3, gb3, nv);
    dim3 gd(NN / 64, NB);
    hipLaunchKernelGGL(diffuse_kernel, gd, dim3(256), 0, stream, nv, x, xs1);
    hipLaunchKernelGGL(diffuse_kernel, gd, dim3(256), 0, stream, nv, xs1, xs2);
    hipLaunchKernelGGL(diffuse_kernel, gd, dim3(256), 0, stream, nv, xs2, xb1);
    hipLaunchKernelGGL(diffuse_kernel, gd, dim3(256), 0, stream, nv, xb1, xb2);
    hipLaunchKernelGGL(attnpool_kernel, dim3(NB, 2), dim3(256), 0, stream,
                       x, xs1, xs2, xs2, xb1, xb2, att_w, att_b, w1, gfb);
    hipLaunchKernelGGL(final_kernel, dim3(NN), dim3(256), 0, stream,
                       emb1, wpf, wpb, bias_pool, x, xs1, xs2, xb1, xb2, gfb, alpha, beta, out);
}

// Round 2
// 764.126 us; speedup vs baseline: 4.1249x; 4.1249x over previous
//
#include <hip/hip_runtime.h>
#include <cmath>

#define NB 32
#define NN 1024
#define NC 64
#define NE 16

__device__ __forceinline__ float sigm(float v) { return 1.0f / (1.0f + expf(-v)); }
__device__ __forceinline__ float lrelu(float v) { return v > 0.0f ? v : 0.01f * v; }

// ---------------- Kernel 1: nv = tanh(tanh(tanh(emb0*filt)*f1)*f2) ----------------
__global__ __launch_bounds__(256) void nv_kernel(
    const float* __restrict__ x, const float* __restrict__ emb0,
    const float* __restrict__ speed, const float* __restrict__ occupy,
    const float* __restrict__ fw1, const float* __restrict__ fb1,
    const float* __restrict__ fw2, const float* __restrict__ fb2,
    const float* __restrict__ fw3, const float* __restrict__ fb3,
    const float* __restrict__ gw1, const float* __restrict__ gb1,
    const float* __restrict__ gw2, const float* __restrict__ gb2,
    const float* __restrict__ gw3, const float* __restrict__ gb3,
    float* __restrict__ nv_out)
{
    const int sub = threadIdx.x >> 6;
    const int lt = threadIdx.x & 63;
    const int row = blockIdx.x * 4 + sub;   // b*N + n

    __shared__ float xr[4][64];
    __shared__ float h1[4][16];
    __shared__ float h2[4][2];
    __shared__ float g1[4][16];
    __shared__ float g2a[4][2];
    __shared__ float g2b[4][2];
    __shared__ float f1s[4][16];

    xr[sub][lt] = x[(size_t)row * 64 + lt];
    if (lt < 16) g1[sub][lt] = sigm(speed[row] * gw1[lt] + gb1[lt]);
    __syncthreads();
    if (lt < 16) {
        float s = fb1[lt];
        #pragma unroll
        for (int i = 0; i < 64; ++i) s += xr[sub][i] * fw1[lt * 64 + i];
        h1[sub][lt] = sigm(s);
    }
    __syncthreads();
    if (lt < 2) {
        float s = fb2[lt];
        #pragma unroll
        for (int i = 0; i < 16; ++i) s += h1[sub][i] * fw2[lt * 16 + i];
        h2[sub][lt] = sigm(s);
        float s2 = gb2[lt];
        #pragma unroll
        for (int i = 0; i < 16; ++i) s2 += g1[sub][i] * gw2[lt * 16 + i];
        g2a[sub][lt] = sigm(s2);
    }
    __syncthreads();
    if (lt < 16) {
        f1s[sub][lt] = g2a[sub][0] * gw3[lt * 2] + g2a[sub][1] * gw3[lt * 2 + 1] + gb3[lt];
        g1[sub][lt] = sigm(occupy[row] * gw1[lt] + gb1[lt]);   // reuse g1 for occupy path
    }
    __syncthreads();
    if (lt < 2) {
        float s2 = gb2[lt];
        #pragma unroll
        for (int i = 0; i < 16; ++i) s2 += g1[sub][i] * gw2[lt * 16 + i];
        g2b[sub][lt] = sigm(s2);
    }
    __syncthreads();
    if (lt < 16) {
        float f2 = g2b[sub][0] * gw3[lt * 2] + g2b[sub][1] * gw3[lt * 2 + 1] + gb3[lt];
        float filt = h2[sub][0] * fw3[lt * 2] + h2[sub][1] * fw3[lt * 2 + 1] + fb3[lt];
        float v = tanhf(emb0[(size_t)row * 16 + lt] * filt);
        v = tanhf(v * f1s[sub][lt]);
        v = tanhf(v * f2);
        nv_out[(size_t)row * 16 + lt] = v;
    }
}

// ------- Kernel 2: y = LeakyReLU(S x) with S-tile = relu(nv nv^T) recomputed on the fly -------
__global__ __launch_bounds__(256) void diffuse_kernel(
    const float* __restrict__ nv, const float* __restrict__ xin,
    float* __restrict__ yout)
{
    const int b = blockIdx.y;
    const int m0 = blockIdx.x * 64;
    const int t = threadIdx.x;
    const int lane = t & 63;
    const int w = t >> 6;
    const int tx = t & 15;
    const int ty = t >> 4;

    __shared__ float nvn[64][16];
    __shared__ float st[64][64];   // st[n][m]
    __shared__ float xt[64][64];   // xt[n][c]

    float4 nvr[4];
    {
        const float4* p = reinterpret_cast<const float4*>(nv + ((size_t)b * NN + m0 + lane) * NE);
        nvr[0] = p[0]; nvr[1] = p[1]; nvr[2] = p[2]; nvr[3] = p[3];
    }
    float acc[4][4];
    #pragma unroll
    for (int i = 0; i < 4; ++i)
        #pragma unroll
        for (int j = 0; j < 4; ++j) acc[i][j] = 0.0f;

    const float4* nvb = reinterpret_cast<const float4*>(nv + (size_t)b * NN * NE);
    const float4* xb4 = reinterpret_cast<const float4*>(xin + (size_t)b * NN * NC);

    for (int n0 = 0; n0 < NN; n0 += 64) {
        __syncthreads();
        reinterpret_cast<float4*>(&nvn[0][0])[t] = nvb[n0 * 4 + t];
        {
            float4* xd = reinterpret_cast<float4*>(&xt[0][0]);
            const float4* xs = xb4 + n0 * 16;
            #pragma unroll
            for (int r = 0; r < 4; ++r) xd[t + 256 * r] = xs[t + 256 * r];
        }
        __syncthreads();

        #pragma unroll
        for (int j = 0; j < 16; ++j) {
            int n = w * 16 + j;
            const float4* q = reinterpret_cast<const float4*>(&nvn[n][0]);
            float4 q0 = q[0], q1 = q[1], q2 = q[2], q3 = q[3];
            float s = nvr[0].x * q0.x + nvr[0].y * q0.y + nvr[0].z * q0.z + nvr[0].w * q0.w
                    + nvr[1].x * q1.x + nvr[1].y * q1.y + nvr[1].z * q1.z + nvr[1].w * q1.w
                    + nvr[2].x * q2.x + nvr[2].y * q2.y + nvr[2].z * q2.z + nvr[2].w * q2.w
                    + nvr[3].x * q3.x + nvr[3].y * q3.y + nvr[3].z * q3.z + nvr[3].w * q3.w;
            st[n][lane] = fmaxf(s, 0.0f);
        }
        __syncthreads();

        #pragma unroll
        for (int n = 0; n < 64; ++n) {
            float4 sv = reinterpret_cast<const float4*>(&st[n][0])[ty];
            float4 xv = reinterpret_cast<const float4*>(&xt[n][0])[tx];
            acc[0][0] += sv.x * xv.x; acc[0][1] += sv.x * xv.y; acc[0][2] += sv.x * xv.z; acc[0][3] += sv.x * xv.w;
            acc[1][0] += sv.y * xv.x; acc[1][1] += sv.y * xv.y; acc[1][2] += sv.y * xv.z; acc[1][3] += sv.y * xv.w;
            acc[2][0] += sv.z * xv.x; acc[2][1] += sv.z * xv.y; acc[2][2] += sv.z * xv.z; acc[2][3] += sv.z * xv.w;
            acc[3][0] += sv.w * xv.x; acc[3][1] += sv.w * xv.y; acc[3][2] += sv.w * xv.z; acc[3][3] += sv.w * xv.w;
        }
    }

    #pragma unroll
    for (int i = 0; i < 4; ++i) {
        float4 v;
        v.x = lrelu(acc[i][0]); v.y = lrelu(acc[i][1]); v.z = lrelu(acc[i][2]); v.w = lrelu(acc[i][3]);
        reinterpret_cast<float4*>(yout + ((size_t)b * NN + m0 + ty * 4 + i) * NC)[tx] = v;
    }
}

// ------- Kernel 3: attention pool for both xg1 and xg2 -------
__global__ __launch_bounds__(256) void attnpool_kernel(
    const float* __restrict__ a0, const float* __restrict__ a1, const float* __restrict__ a2,
    const float* __restrict__ c0, const float* __restrict__ c1, const float* __restrict__ c2,
    const float* __restrict__ att_w, const float* __restrict__ att_b,
    const float* __restrict__ w1, float* __restrict__ gf_out)
{
    const int b = blockIdx.x;
    const int which = blockIdx.y;
    const float* p0 = which ? c0 : a0;
    const float* p1 = which ? c1 : a1;
    const float* p2 = which ? c2 : a2;
    const int t = threadIdx.x;
    const int lane = t & 63;
    const int w = t >> 6;

    __shared__ float sc[NN];
    __shared__ float red[4];
    __shared__ float gfp[4][64];
    __shared__ float gfin[64];

    const float aw = att_w[lane];
    const size_t base = (size_t)b * NN * NC;

    for (int n = w; n < NN; n += 4) {
        size_t idx = base + (size_t)n * NC + lane;
        float nf = (p0[idx] + p1[idx] + p2[idx]) * (1.0f / 3.0f);
        float v = nf * aw;
        #pragma unroll
        for (int off = 32; off > 0; off >>= 1) v += __shfl_xor(v, off);
        if (lane == 0) sc[n] = v + att_b[0];
    }
    __syncthreads();
    float m = -INFINITY;
    for (int i = t; i < NN; i += 256) m = fmaxf(m, sc[i]);
    #pragma unroll
    for (int off = 32; off > 0; off >>= 1) m = fmaxf(m, __shfl_xor(m, off));
    if (lane == 0) red[w] = m;
    __syncthreads();
    m = fmaxf(fmaxf(red[0], red[1]), fmaxf(red[2], red[3]));
    __syncthreads();
    float s = 0.0f;
    for (int i = t; i < NN; i += 256) { float e = expf(sc[i] - m); sc[i] = e; s += e; }
    #pragma unroll
    for (int off = 32; off > 0; off >>= 1) s += __shfl_xor(s, off);
    if (lane == 0) red[w] = s;
    __syncthreads();
    const float inv_denom = 1.0f / (red[0] + red[1] + red[2] + red[3]);

    float acc = 0.0f;
    for (int n = w; n < NN; n += 4) {
        size_t idx = base + (size_t)n * NC + lane;
        float nf = (p0[idx] + p1[idx] + p2[idx]) * (1.0f / 3.0f);
        acc += nf * sc[n];
    }
    gfp[w][lane] = acc;
    __syncthreads();
    if (w == 0) gfin[lane] = (gfp[0][lane] + gfp[1][lane] + gfp[2][lane] + gfp[3][lane]) * inv_denom;
    __syncthreads();
    if (w == 0) {
        float s2 = 0.0f;
        #pragma unroll
        for (int c = 0; c < 64; ++c) s2 += gfin[c] * w1[c * 64 + lane];
        gf_out[((size_t)which * NB + b) * 64 + lane] = s2;
    }
}

// ------- Kernel 4a: W[n][ki][o] = sum_e emb1[n,e] * pool[e][ki][o]  (pool streamed once) -------
__global__ __launch_bounds__(256) void wbuild_kernel(
    const float* __restrict__ emb1, const float* __restrict__ pool,
    float* __restrict__ W)
{
    const int ki = blockIdx.x;            // 0..191  (k*64+i)
    const int t = threadIdx.x;
    const int o = t & 63;

    __shared__ float slab[16][64];        // pool[e][ki][:]
    __shared__ float eloc[256][16];

    for (int idx = t; idx < 1024; idx += 256)
        slab[idx >> 6][idx & 63] = pool[((size_t)(idx >> 6) * 192 + ki) * 64 + (idx & 63)];

    for (int chunk = 0; chunk < 4; ++chunk) {
        __syncthreads();
        for (int idx = t; idx < 4096; idx += 256)
            eloc[idx >> 4][idx & 15] = emb1[((size_t)chunk * 256 + (idx >> 4)) * 16 + (idx & 15)];
        __syncthreads();
        for (int nl = t >> 6; nl < 256; nl += 4) {
            float s = 0.0f;
            #pragma unroll
            for (int e = 0; e < 16; ++e) s += eloc[nl][e] * slab[e][o];
            W[((size_t)(chunk * 256 + nl) * 192 + ki) * 64 + o] = s;
        }
    }
}

// ------- Kernel 4b: per node n, out[b,o] (pass0: = a*d + bias + gf; pass1: += b*d) -------
__global__ __launch_bounds__(256) void apply_kernel(
    const float* __restrict__ W, const float* __restrict__ emb1,
    const float* __restrict__ bias_pool,
    const float* __restrict__ s0, const float* __restrict__ s1, const float* __restrict__ s2,
    const float* __restrict__ gf, const float* __restrict__ scale,
    float* __restrict__ out, int pass)
{
    const int n = blockIdx.x;
    const int t = threadIdx.x;
    const int o = t & 63;
    const int bg = t >> 6;

    __shared__ float Wn[192][64];      // 48 KB
    __shared__ float Xs[3][32][64];    // 24 KB
    __shared__ float e1s[16];

    if (t < 16) e1s[t] = emb1[n * 16 + t];
    {
        const float4* src = reinterpret_cast<const float4*>(W + (size_t)n * 192 * 64);
        float4* dst = reinterpret_cast<float4*>(&Wn[0][0]);
        #pragma unroll
        for (int r = 0; r < 12; ++r) dst[t + 256 * r] = src[t + 256 * r];
    }
    const float* srcs[3] = {s0, s1, s2};
    #pragma unroll
    for (int k = 0; k < 3; ++k) {
        const float* sp = srcs[k];
        #pragma unroll
        for (int r = 0; r < 2; ++r) {
            int idx = t + 256 * r;
            int b = idx >> 4, i4 = idx & 15;
            reinterpret_cast<float4*>(&Xs[k][b][0])[i4] =
                reinterpret_cast<const float4*>(sp + ((size_t)b * NN + n) * NC)[i4];
        }
    }
    __syncthreads();

    float acc[8] = {};
    #pragma unroll 4
    for (int ki = 0; ki < 192; ++ki) {
        float wv = Wn[ki][o];
        int k = ki >> 6, i = ki & 63;
        #pragma unroll
        for (int j = 0; j < 8; ++j) acc[j] += Xs[k][bg * 8 + j][i] * wv;
    }

    const float sc = scale[0];
    if (pass == 0) {
        float bias_o = 0.0f;
        #pragma unroll
        for (int e = 0; e < 16; ++e) bias_o += e1s[e] * bias_pool[e * 64 + o];
        #pragma unroll
        for (int j = 0; j < 8; ++j) {
            int b = bg * 8 + j;
            float g = gf[(size_t)b * 64 + o] + gf[((size_t)NB + b) * 64 + o];
            out[((size_t)b * NN + n) * NC + o] = sc * acc[j] + bias_o + g;
        }
    } else {
        #pragma unroll
        for (int j = 0; j < 8; ++j) {
            int b = bg * 8 + j;
            out[((size_t)b * NN + n) * NC + o] += sc * acc[j];
        }
    }
}

// ------- Fallback (old) final kernel, used only if ws_size is too small for W -------
__global__ __launch_bounds__(256) void final_kernel(
    const float* __restrict__ emb1,
    const float* __restrict__ wpf, const float* __restrict__ wpb,
    const float* __restrict__ bias_pool,
    const float* __restrict__ x, const float* __restrict__ xs1, const float* __restrict__ xs2,
    const float* __restrict__ xb1, const float* __restrict__ xb2,
    const float* __restrict__ gf, const float* __restrict__ alpha, const float* __restrict__ beta,
    float* __restrict__ out)
{
    const int n = blockIdx.x;
    const int t = threadIdx.x;
    const int o = t & 63;
    const int bg = t >> 6;

    __shared__ float Wk[64][64];
    __shared__ float xk[32][64];
    __shared__ float e1[16];
    if (t < 16) e1[t] = emb1[n * 16 + t];

    float acc[2][8];
    #pragma unroll
    for (int d = 0; d < 2; ++d)
        #pragma unroll
        for (int j = 0; j < 8; ++j) acc[d][j] = 0.0f;

    const float* srcs[2][3] = {{x, xs1, xs2}, {xs2, xb1, xb2}};

    #pragma unroll
    for (int dir = 0; dir < 2; ++dir) {
        const float* wp = dir ? wpb : wpf;
        #pragma unroll
        for (int k = 0; k < 3; ++k) {
            __syncthreads();
            for (int idx = t; idx < 4096; idx += 256) {
                int i = idx >> 6, oo = idx & 63;
                float s = 0.0f;
                #pragma unroll
                for (int e = 0; e < 16; ++e) s += e1[e] * wp[(((size_t)e * 3 + k) * 64 + i) * 64 + oo];
                Wk[i][oo] = s;
            }
            const float* src = srcs[dir][k];
            for (int idx = t; idx < 2048; idx += 256) {
                int bb = idx >> 6, ii = idx & 63;
                xk[bb][ii] = src[((size_t)bb * NN + n) * NC + ii];
            }
            __syncthreads();
            #pragma unroll
            for (int j = 0; j < 8; ++j) {
                int bb = bg * 8 + j;
                float s = 0.0f;
                #pragma unroll
                for (int i = 0; i < 64; i += 4) {
                    float4 xv = *reinterpret_cast<const float4*>(&xk[bb][i]);
                    s += xv.x * Wk[i][o] + xv.y * Wk[i + 1][o] + xv.z * Wk[i + 2][o] + xv.w * Wk[i + 3][o];
                }
                acc[dir][j] += s;
            }
        }
    }

    float bias_o = 0.0f;
    #pragma unroll
    for (int e = 0; e < 16; ++e) bias_o += e1[e] * bias_pool[e * 64 + o];
    const float al = alpha[0], be = beta[0];
    #pragma unroll
    for (int j = 0; j < 8; ++j) {
        int bb = bg * 8 + j;
        float g = gf[(size_t)bb * 64 + o] + gf[((size_t)NB + bb) * 64 + o];
        out[((size_t)bb * NN + n) * NC + o] = al * acc[0][j] + be * acc[1][j] + bias_o + g;
    }
}

extern "C" void kernel_launch(void* const* d_in, const int* in_sizes, int n_in,
                              void* d_out, int out_size, void* d_ws, size_t ws_size,
                              hipStream_t stream)
{
    const float* x      = (const float*)d_in[0];
    const float* emb0   = (const float*)d_in[1];
    const float* emb1   = (const float*)d_in[2];
    const float* speed  = (const float*)d_in[5];
    const float* occupy = (const float*)d_in[6];
    const float* fw1 = (const float*)d_in[7];
    const float* fb1 = (const float*)d_in[8];
    const float* fw2 = (const float*)d_in[9];
    const float* fb2 = (const float*)d_in[10];
    const float* fw3 = (const float*)d_in[11];
    const float* fb3 = (const float*)d_in[12];
    const float* gw1 = (const float*)d_in[13];
    const float* gb1 = (const float*)d_in[14];
    const float* gw2 = (const float*)d_in[15];
    const float* gb2 = (const float*)d_in[16];
    const float* gw3 = (const float*)d_in[17];
    const float* gb3 = (const float*)d_in[18];
    const float* alpha = (const float*)d_in[19];
    const float* beta  = (const float*)d_in[20];
    const float* wpf = (const float*)d_in[21];
    const float* wpb = (const float*)d_in[22];
    const float* bias_pool = (const float*)d_in[23];
    const float* w1 = (const float*)d_in[24];
    const float* att_w = (const float*)d_in[25];
    const float* att_b = (const float*)d_in[26];
    float* out = (float*)d_out;

    float* ws = (float*)d_ws;
    float* nv  = ws;                                   // B*N*E      = 524288
    float* xs1 = nv + (size_t)NB * NN * NE;            // B*N*C each = 2097152
    float* xs2 = xs1 + (size_t)NB * NN * NC;
    float* xb1 = xs2 + (size_t)NB * NN * NC;
    float* xb2 = xb1 + (size_t)NB * NN * NC;
    float* gfb = xb2 + (size_t)NB * NN * NC;           // [2][B][64] = 4096
    float* Wbuf = gfb + 4096;                          // N*K*C*O    = 12582912

    const size_t need_bytes =
        ((size_t)NB * NN * NE + 4 * (size_t)NB * NN * NC + 4096 +
         (size_t)NN * 3 * NC * NC) * sizeof(float);

    hipLaunchKernelGGL(nv_kernel, dim3(NB * NN / 4), dim3(256), 0, stream,
                       x, emb0, speed, occupy, fw1, fb1, fw2, fb2, fw3, fb3,
                       gw1, gb1, gw2, gb2, gw3, gb3, nv);
    dim3 gd(NN / 64, NB);
    hipLaunchKernelGGL(diffuse_kernel, gd, dim3(256), 0, stream, nv, x, xs1);
    hipLaunchKernelGGL(diffuse_kernel, gd, dim3(256), 0, stream, nv, xs1, xs2);
    hipLaunchKernelGGL(diffuse_kernel, gd, dim3(256), 0, stream, nv, xs2, xb1);
    hipLaunchKernelGGL(diffuse_kernel, gd, dim3(256), 0, stream, nv, xb1, xb2);
    hipLaunchKernelGGL(attnpool_kernel, dim3(NB, 2), dim3(256), 0, stream,
                       x, xs1, xs2, xs2, xb1, xb2, att_w, att_b, w1, gfb);

    if (ws_size >= need_bytes) {
        // forward pass: out = alpha*d1 + bias + gf + gf1
        hipLaunchKernelGGL(wbuild_kernel, dim3(192), dim3(256), 0, stream, emb1, wpf, Wbuf);
        hipLaunchKernelGGL(apply_kernel, dim3(NN), dim3(256), 0, stream,
                           Wbuf, emb1, bias_pool, x, xs1, xs2, gfb, alpha, out, 0);
        // backward pass: out += beta*d2
        hipLaunchKernelGGL(wbuild_kernel, dim3(192), dim3(256), 0, stream, emb1, wpb, Wbuf);
        hipLaunchKernelGGL(apply_kernel, dim3(NN), dim3(256), 0, stream,
                           Wbuf, emb1, bias_pool, xs2, xb1, xb2, gfb, beta, out, 1);
    } else {
        hipLaunchKernelGGL(final_kernel, dim3(NN), dim3(256), 0, stream,
                           emb1, wpf, wpb, bias_pool, x, xs1, xs2, xb1, xb2, gfb, alpha, beta, out);
    }
}

// Round 3
// 563.630 us; speedup vs baseline: 5.5922x; 1.3557x over previous
//
#include <hip/hip_runtime.h>
#include <cmath>

#define NB 32
#define NN 1024
#define NC 64
#define NE 16

__device__ __forceinline__ float sigm(float v) { return 1.0f / (1.0f + expf(-v)); }
__device__ __forceinline__ float lrelu(float v) { return v > 0.0f ? v : 0.01f * v; }

// ---------------- Kernel 1: nv = tanh(tanh(tanh(emb0*filt)*f1)*f2) ----------------
__global__ __launch_bounds__(256) void nv_kernel(
    const float* __restrict__ x, const float* __restrict__ emb0,
    const float* __restrict__ speed, const float* __restrict__ occupy,
    const float* __restrict__ fw1, const float* __restrict__ fb1,
    const float* __restrict__ fw2, const float* __restrict__ fb2,
    const float* __restrict__ fw3, const float* __restrict__ fb3,
    const float* __restrict__ gw1, const float* __restrict__ gb1,
    const float* __restrict__ gw2, const float* __restrict__ gb2,
    const float* __restrict__ gw3, const float* __restrict__ gb3,
    float* __restrict__ nv_out)
{
    const int sub = threadIdx.x >> 6;
    const int lt = threadIdx.x & 63;
    const int row = blockIdx.x * 4 + sub;   // b*N + n

    __shared__ float xr[4][64];
    __shared__ float h1[4][16];
    __shared__ float h2[4][2];
    __shared__ float g1[4][16];
    __shared__ float g2a[4][2];
    __shared__ float g2b[4][2];
    __shared__ float f1s[4][16];

    xr[sub][lt] = x[(size_t)row * 64 + lt];
    if (lt < 16) g1[sub][lt] = sigm(speed[row] * gw1[lt] + gb1[lt]);
    __syncthreads();
    if (lt < 16) {
        float s = fb1[lt];
        #pragma unroll
        for (int i = 0; i < 64; ++i) s += xr[sub][i] * fw1[lt * 64 + i];
        h1[sub][lt] = sigm(s);
    }
    __syncthreads();
    if (lt < 2) {
        float s = fb2[lt];
        #pragma unroll
        for (int i = 0; i < 16; ++i) s += h1[sub][i] * fw2[lt * 16 + i];
        h2[sub][lt] = sigm(s);
        float s2 = gb2[lt];
        #pragma unroll
        for (int i = 0; i < 16; ++i) s2 += g1[sub][i] * gw2[lt * 16 + i];
        g2a[sub][lt] = sigm(s2);
    }
    __syncthreads();
    if (lt < 16) {
        f1s[sub][lt] = g2a[sub][0] * gw3[lt * 2] + g2a[sub][1] * gw3[lt * 2 + 1] + gb3[lt];
        g1[sub][lt] = sigm(occupy[row] * gw1[lt] + gb1[lt]);   // reuse g1 for occupy path
    }
    __syncthreads();
    if (lt < 2) {
        float s2 = gb2[lt];
        #pragma unroll
        for (int i = 0; i < 16; ++i) s2 += g1[sub][i] * gw2[lt * 16 + i];
        g2b[sub][lt] = sigm(s2);
    }
    __syncthreads();
    if (lt < 16) {
        float f2 = g2b[sub][0] * gw3[lt * 2] + g2b[sub][1] * gw3[lt * 2 + 1] + gb3[lt];
        float filt = h2[sub][0] * fw3[lt * 2] + h2[sub][1] * fw3[lt * 2 + 1] + fb3[lt];
        float v = tanhf(emb0[(size_t)row * 16 + lt] * filt);
        v = tanhf(v * f1s[sub][lt]);
        v = tanhf(v * f2);
        nv_out[(size_t)row * 16 + lt] = v;
    }
}

// ------- Kernel 2: y = LeakyReLU(S x) with S-tile = relu(nv nv^T) recomputed on the fly -------
__global__ __launch_bounds__(256) void diffuse_kernel(
    const float* __restrict__ nv, const float* __restrict__ xin,
    float* __restrict__ yout)
{
    const int b = blockIdx.y;
    const int m0 = blockIdx.x * 64;
    const int t = threadIdx.x;
    const int lane = t & 63;
    const int w = t >> 6;
    const int tx = t & 15;
    const int ty = t >> 4;

    __shared__ float nvn[64][16];
    __shared__ float st[64][64];   // st[n][m]
    __shared__ float xt[64][64];   // xt[n][c]

    float4 nvr[4];
    {
        const float4* p = reinterpret_cast<const float4*>(nv + ((size_t)b * NN + m0 + lane) * NE);
        nvr[0] = p[0]; nvr[1] = p[1]; nvr[2] = p[2]; nvr[3] = p[3];
    }
    float acc[4][4];
    #pragma unroll
    for (int i = 0; i < 4; ++i)
        #pragma unroll
        for (int j = 0; j < 4; ++j) acc[i][j] = 0.0f;

    const float4* nvb = reinterpret_cast<const float4*>(nv + (size_t)b * NN * NE);
    const float4* xb4 = reinterpret_cast<const float4*>(xin + (size_t)b * NN * NC);

    for (int n0 = 0; n0 < NN; n0 += 64) {
        __syncthreads();
        reinterpret_cast<float4*>(&nvn[0][0])[t] = nvb[n0 * 4 + t];
        {
            float4* xd = reinterpret_cast<float4*>(&xt[0][0]);
            const float4* xs = xb4 + n0 * 16;
            #pragma unroll
            for (int r = 0; r < 4; ++r) xd[t + 256 * r] = xs[t + 256 * r];
        }
        __syncthreads();

        #pragma unroll
        for (int j = 0; j < 16; ++j) {
            int n = w * 16 + j;
            const float4* q = reinterpret_cast<const float4*>(&nvn[n][0]);
            float4 q0 = q[0], q1 = q[1], q2 = q[2], q3 = q[3];
            float s = nvr[0].x * q0.x + nvr[0].y * q0.y + nvr[0].z * q0.z + nvr[0].w * q0.w
                    + nvr[1].x * q1.x + nvr[1].y * q1.y + nvr[1].z * q1.z + nvr[1].w * q1.w
                    + nvr[2].x * q2.x + nvr[2].y * q2.y + nvr[2].z * q2.z + nvr[2].w * q2.w
                    + nvr[3].x * q3.x + nvr[3].y * q3.y + nvr[3].z * q3.z + nvr[3].w * q3.w;
            st[n][lane] = fmaxf(s, 0.0f);
        }
        __syncthreads();

        #pragma unroll
        for (int n = 0; n < 64; ++n) {
            float4 sv = reinterpret_cast<const float4*>(&st[n][0])[ty];
            float4 xv = reinterpret_cast<const float4*>(&xt[n][0])[tx];
            acc[0][0] += sv.x * xv.x; acc[0][1] += sv.x * xv.y; acc[0][2] += sv.x * xv.z; acc[0][3] += sv.x * xv.w;
            acc[1][0] += sv.y * xv.x; acc[1][1] += sv.y * xv.y; acc[1][2] += sv.y * xv.z; acc[1][3] += sv.y * xv.w;
            acc[2][0] += sv.z * xv.x; acc[2][1] += sv.z * xv.y; acc[2][2] += sv.z * xv.z; acc[2][3] += sv.z * xv.w;
            acc[3][0] += sv.w * xv.x; acc[3][1] += sv.w * xv.y; acc[3][2] += sv.w * xv.z; acc[3][3] += sv.w * xv.w;
        }
    }

    #pragma unroll
    for (int i = 0; i < 4; ++i) {
        float4 v;
        v.x = lrelu(acc[i][0]); v.y = lrelu(acc[i][1]); v.z = lrelu(acc[i][2]); v.w = lrelu(acc[i][3]);
        reinterpret_cast<float4*>(yout + ((size_t)b * NN + m0 + ty * 4 + i) * NC)[tx] = v;
    }
}

// ======= Attention pool, stage A: per-row scores (one wave per row) =======
// row index r = which*(B*N) + b*N + n
__global__ __launch_bounds__(256) void scores_kernel(
    const float* __restrict__ x, const float* __restrict__ xs1, const float* __restrict__ xs2,
    const float* __restrict__ xb1, const float* __restrict__ xb2,
    const float* __restrict__ att_w, const float* __restrict__ att_b,
    float* __restrict__ sc)
{
    const int lane = threadIdx.x & 63;
    const int w = threadIdx.x >> 6;
    const int r = blockIdx.x * 4 + w;
    const int which = r >= NB * NN;
    const int rr = r - which * NB * NN;

    const float* p0 = which ? xs2 : x;
    const float* p1 = which ? xb1 : xs1;
    const float* p2 = which ? xb2 : xs2;

    size_t idx = (size_t)rr * NC + lane;
    float nf = (p0[idx] + p1[idx] + p2[idx]) * (1.0f / 3.0f);
    float v = nf * att_w[lane];
    #pragma unroll
    for (int off = 32; off > 0; off >>= 1) v += __shfl_xor(v, off);
    if (lane == 0) sc[r] = v + att_b[0];
}

// ======= Stage B: softmax over the 1024 nodes of one (which,b); writes normalized weights =======
__global__ __launch_bounds__(256) void softmax_kernel(float* __restrict__ sc)
{
    const int wb = blockIdx.x;            // which*NB + b
    const int t = threadIdx.x;
    const int lane = t & 63;
    const int w = t >> 6;
    float* p = sc + (size_t)wb * NN;

    __shared__ float red[4];
    float4 v = reinterpret_cast<const float4*>(p)[t];
    float m = fmaxf(fmaxf(v.x, v.y), fmaxf(v.z, v.w));
    #pragma unroll
    for (int off = 32; off > 0; off >>= 1) m = fmaxf(m, __shfl_xor(m, off));
    if (lane == 0) red[w] = m;
    __syncthreads();
    m = fmaxf(fmaxf(red[0], red[1]), fmaxf(red[2], red[3]));
    __syncthreads();
    v.x = expf(v.x - m); v.y = expf(v.y - m); v.z = expf(v.z - m); v.w = expf(v.w - m);
    float s = v.x + v.y + v.z + v.w;
    #pragma unroll
    for (int off = 32; off > 0; off >>= 1) s += __shfl_xor(s, off);
    if (lane == 0) red[w] = s;
    __syncthreads();
    const float inv = 1.0f / (red[0] + red[1] + red[2] + red[3]);
    v.x *= inv; v.y *= inv; v.z *= inv; v.w *= inv;
    reinterpret_cast<float4*>(p)[t] = v;
}

// ======= Stage C: partial weighted sums over 64-node chunks =======
__global__ __launch_bounds__(256) void poolpart_kernel(
    const float* __restrict__ x, const float* __restrict__ xs1, const float* __restrict__ xs2,
    const float* __restrict__ xb1, const float* __restrict__ xb2,
    const float* __restrict__ sc, float* __restrict__ partial)
{
    const int chunk = blockIdx.x;         // 0..15
    const int b = blockIdx.y;
    const int which = blockIdx.z;
    const int lane = threadIdx.x & 63;
    const int w = threadIdx.x >> 6;

    const float* p0 = which ? xs2 : x;
    const float* p1 = which ? xb1 : xs1;
    const float* p2 = which ? xb2 : xs2;

    const int n0 = chunk * 64;
    const size_t base = (size_t)b * NN;
    float acc = 0.0f;
    for (int j = w; j < 64; j += 4) {
        int n = n0 + j;
        size_t idx = (base + n) * NC + lane;
        float nf = (p0[idx] + p1[idx] + p2[idx]) * (1.0f / 3.0f);
        acc += nf * sc[((size_t)which * NB + b) * NN + n];
    }
    __shared__ float red[4][64];
    red[w][lane] = acc;
    __syncthreads();
    if (w == 0) {
        float s = red[0][lane] + red[1][lane] + red[2][lane] + red[3][lane];
        partial[(((size_t)which * NB + b) * 16 + chunk) * 64 + lane] = s;
    }
}

// ======= Stage D: reduce partials + multiply by weights1 =======
__global__ __launch_bounds__(256) void poolfin_kernel(
    const float* __restrict__ partial, const float* __restrict__ w1,
    float* __restrict__ gf_out)
{
    const int wb = blockIdx.x;            // which*NB + b
    const int t = threadIdx.x;
    const int lane = t & 63;
    const int w = t >> 6;

    __shared__ float red[4][64];
    __shared__ float gfin[64];
    float acc = 0.0f;
    #pragma unroll
    for (int r = w; r < 16; r += 4)
        acc += partial[((size_t)wb * 16 + r) * 64 + lane];
    red[w][lane] = acc;
    __syncthreads();
    if (w == 0) gfin[lane] = red[0][lane] + red[1][lane] + red[2][lane] + red[3][lane];
    __syncthreads();
    if (w == 0) {
        float s = 0.0f;
        #pragma unroll
        for (int c = 0; c < 64; ++c) s += gfin[c] * w1[c * 64 + lane];
        gf_out[(size_t)wb * 64 + lane] = s;
    }
}

// ------- Kernel 4a: W[n][ki][o] = sum_e emb1[n,e] * pool[e][ki][o] -------
__global__ __launch_bounds__(256) void wbuild_kernel(
    const float* __restrict__ emb1, const float* __restrict__ pool,
    float* __restrict__ W)
{
    const int ki = blockIdx.x;            // 0..191  (k*64+i)
    const int t = threadIdx.x;
    const int o = t & 63;

    __shared__ float slab[16][64];
    __shared__ float eloc[256][16];

    for (int idx = t; idx < 1024; idx += 256)
        slab[idx >> 6][idx & 63] = pool[((size_t)(idx >> 6) * 192 + ki) * 64 + (idx & 63)];

    for (int chunk = 0; chunk < 4; ++chunk) {
        __syncthreads();
        for (int idx = t; idx < 4096; idx += 256)
            eloc[idx >> 4][idx & 15] = emb1[((size_t)chunk * 256 + (idx >> 4)) * 16 + (idx & 15)];
        __syncthreads();
        for (int nl = t >> 6; nl < 256; nl += 4) {
            float s = 0.0f;
            #pragma unroll
            for (int e = 0; e < 16; ++e) s += eloc[nl][e] * slab[e][o];
            W[((size_t)(chunk * 256 + nl) * 192 + ki) * 64 + o] = s;
        }
    }
}

// ------- Kernel 4b: per node n, out[b,o] (pass0: = a*d + bias + gf; pass1: += b*d) -------
__global__ __launch_bounds__(256) void apply_kernel(
    const float* __restrict__ W, const float* __restrict__ emb1,
    const float* __restrict__ bias_pool,
    const float* __restrict__ s0, const float* __restrict__ s1, const float* __restrict__ s2,
    const float* __restrict__ gf, const float* __restrict__ scale,
    float* __restrict__ out, int pass)
{
    const int n = blockIdx.x;
    const int t = threadIdx.x;
    const int o = t & 63;
    const int bg = t >> 6;

    __shared__ float Wn[192][64];      // 48 KB
    __shared__ float Xs[3][32][64];    // 24 KB
    __shared__ float e1s[16];

    if (t < 16) e1s[t] = emb1[n * 16 + t];
    {
        const float4* src = reinterpret_cast<const float4*>(W + (size_t)n * 192 * 64);
        float4* dst = reinterpret_cast<float4*>(&Wn[0][0]);
        #pragma unroll
        for (int r = 0; r < 12; ++r) dst[t + 256 * r] = src[t + 256 * r];
    }
    const float* srcs[3] = {s0, s1, s2};
    #pragma unroll
    for (int k = 0; k < 3; ++k) {
        const float* sp = srcs[k];
        #pragma unroll
        for (int r = 0; r < 2; ++r) {
            int idx = t + 256 * r;
            int b = idx >> 4, i4 = idx & 15;
            reinterpret_cast<float4*>(&Xs[k][b][0])[i4] =
                reinterpret_cast<const float4*>(sp + ((size_t)b * NN + n) * NC)[i4];
        }
    }
    __syncthreads();

    float acc[8] = {};
    #pragma unroll 4
    for (int ki = 0; ki < 192; ++ki) {
        float wv = Wn[ki][o];
        int k = ki >> 6, i = ki & 63;
        #pragma unroll
        for (int j = 0; j < 8; ++j) acc[j] += Xs[k][bg * 8 + j][i] * wv;
    }

    const float sc = scale[0];
    if (pass == 0) {
        float bias_o = 0.0f;
        #pragma unroll
        for (int e = 0; e < 16; ++e) bias_o += e1s[e] * bias_pool[e * 64 + o];
        #pragma unroll
        for (int j = 0; j < 8; ++j) {
            int b = bg * 8 + j;
            float g = gf[(size_t)b * 64 + o] + gf[((size_t)NB + b) * 64 + o];
            out[((size_t)b * NN + n) * NC + o] = sc * acc[j] + bias_o + g;
        }
    } else {
        #pragma unroll
        for (int j = 0; j < 8; ++j) {
            int b = bg * 8 + j;
            out[((size_t)b * NN + n) * NC + o] += sc * acc[j];
        }
    }
}

// ------- Fallback final kernel (ws too small) -------
__global__ __launch_bounds__(256) void final_kernel(
    const float* __restrict__ emb1,
    const float* __restrict__ wpf, const float* __restrict__ wpb,
    const float* __restrict__ bias_pool,
    const float* __restrict__ x, const float* __restrict__ xs1, const float* __restrict__ xs2,
    const float* __restrict__ xb1, const float* __restrict__ xb2,
    const float* __restrict__ gf, const float* __restrict__ alpha, const float* __restrict__ beta,
    float* __restrict__ out)
{
    const int n = blockIdx.x;
    const int t = threadIdx.x;
    const int o = t & 63;
    const int bg = t >> 6;

    __shared__ float Wk[64][64];
    __shared__ float xk[32][64];
    __shared__ float e1[16];
    if (t < 16) e1[t] = emb1[n * 16 + t];

    float acc[2][8];
    #pragma unroll
    for (int d = 0; d < 2; ++d)
        #pragma unroll
        for (int j = 0; j < 8; ++j) acc[d][j] = 0.0f;

    const float* srcs[2][3] = {{x, xs1, xs2}, {xs2, xb1, xb2}};

    #pragma unroll
    for (int dir = 0; dir < 2; ++dir) {
        const float* wp = dir ? wpb : wpf;
        #pragma unroll
        for (int k = 0; k < 3; ++k) {
            __syncthreads();
            for (int idx = t; idx < 4096; idx += 256) {
                int i = idx >> 6, oo = idx & 63;
                float s = 0.0f;
                #pragma unroll
                for (int e = 0; e < 16; ++e) s += e1[e] * wp[(((size_t)e * 3 + k) * 64 + i) * 64 + oo];
                Wk[i][oo] = s;
            }
            const float* src = srcs[dir][k];
            for (int idx = t; idx < 2048; idx += 256) {
                int bb = idx >> 6, ii = idx & 63;
                xk[bb][ii] = src[((size_t)bb * NN + n) * NC + ii];
            }
            __syncthreads();
            #pragma unroll
            for (int j = 0; j < 8; ++j) {
                int bb = bg * 8 + j;
                float s = 0.0f;
                #pragma unroll
                for (int i = 0; i < 64; i += 4) {
                    float4 xv = *reinterpret_cast<const float4*>(&xk[bb][i]);
                    s += xv.x * Wk[i][o] + xv.y * Wk[i + 1][o] + xv.z * Wk[i + 2][o] + xv.w * Wk[i + 3][o];
                }
                acc[dir][j] += s;
            }
        }
    }

    float bias_o = 0.0f;
    #pragma unroll
    for (int e = 0; e < 16; ++e) bias_o += e1[e] * bias_pool[e * 64 + o];
    const float al = alpha[0], be = beta[0];
    #pragma unroll
    for (int j = 0; j < 8; ++j) {
        int bb = bg * 8 + j;
        float g = gf[(size_t)bb * 64 + o] + gf[((size_t)NB + bb) * 64 + o];
        out[((size_t)bb * NN + n) * NC + o] = al * acc[0][j] + be * acc[1][j] + bias_o + g;
    }
}

// ------- Fallback attnpool (ws too small) -------
__global__ __launch_bounds__(256) void attnpool_kernel(
    const float* __restrict__ a0, const float* __restrict__ a1, const float* __restrict__ a2,
    const float* __restrict__ c0, const float* __restrict__ c1, const float* __restrict__ c2,
    const float* __restrict__ att_w, const float* __restrict__ att_b,
    const float* __restrict__ w1, float* __restrict__ gf_out)
{
    const int b = blockIdx.x;
    const int which = blockIdx.y;
    const float* p0 = which ? c0 : a0;
    const float* p1 = which ? c1 : a1;
    const float* p2 = which ? c2 : a2;
    const int t = threadIdx.x;
    const int lane = t & 63;
    const int w = t >> 6;

    __shared__ float sc[NN];
    __shared__ float red[4];
    __shared__ float gfp[4][64];
    __shared__ float gfin[64];

    const float aw = att_w[lane];
    const size_t base = (size_t)b * NN * NC;

    for (int n = w; n < NN; n += 4) {
        size_t idx = base + (size_t)n * NC + lane;
        float nf = (p0[idx] + p1[idx] + p2[idx]) * (1.0f / 3.0f);
        float v = nf * aw;
        #pragma unroll
        for (int off = 32; off > 0; off >>= 1) v += __shfl_xor(v, off);
        if (lane == 0) sc[n] = v + att_b[0];
    }
    __syncthreads();
    float m = -INFINITY;
    for (int i = t; i < NN; i += 256) m = fmaxf(m, sc[i]);
    #pragma unroll
    for (int off = 32; off > 0; off >>= 1) m = fmaxf(m, __shfl_xor(m, off));
    if (lane == 0) red[w] = m;
    __syncthreads();
    m = fmaxf(fmaxf(red[0], red[1]), fmaxf(red[2], red[3]));
    __syncthreads();
    float s = 0.0f;
    for (int i = t; i < NN; i += 256) { float e = expf(sc[i] - m); sc[i] = e; s += e; }
    #pragma unroll
    for (int off = 32; off > 0; off >>= 1) s += __shfl_xor(s, off);
    if (lane == 0) red[w] = s;
    __syncthreads();
    const float inv_denom = 1.0f / (red[0] + red[1] + red[2] + red[3]);

    float acc = 0.0f;
    for (int n = w; n < NN; n += 4) {
        size_t idx = base + (size_t)n * NC + lane;
        float nf = (p0[idx] + p1[idx] + p2[idx]) * (1.0f / 3.0f);
        acc += nf * sc[n];
    }
    gfp[w][lane] = acc;
    __syncthreads();
    if (w == 0) gfin[lane] = (gfp[0][lane] + gfp[1][lane] + gfp[2][lane] + gfp[3][lane]) * inv_denom;
    __syncthreads();
    if (w == 0) {
        float s2 = 0.0f;
        #pragma unroll
        for (int c = 0; c < 64; ++c) s2 += gfin[c] * w1[c * 64 + lane];
        gf_out[((size_t)which * NB + b) * 64 + lane] = s2;
    }
}

extern "C" void kernel_launch(void* const* d_in, const int* in_sizes, int n_in,
                              void* d_out, int out_size, void* d_ws, size_t ws_size,
                              hipStream_t stream)
{
    const float* x      = (const float*)d_in[0];
    const float* emb0   = (const float*)d_in[1];
    const float* emb1   = (const float*)d_in[2];
    const float* speed  = (const float*)d_in[5];
    const float* occupy = (const float*)d_in[6];
    const float* fw1 = (const float*)d_in[7];
    const float* fb1 = (const float*)d_in[8];
    const float* fw2 = (const float*)d_in[9];
    const float* fb2 = (const float*)d_in[10];
    const float* fw3 = (const float*)d_in[11];
    const float* fb3 = (const float*)d_in[12];
    const float* gw1 = (const float*)d_in[13];
    const float* gb1 = (const float*)d_in[14];
    const float* gw2 = (const float*)d_in[15];
    const float* gb2 = (const float*)d_in[16];
    const float* gw3 = (const float*)d_in[17];
    const float* gb3 = (const float*)d_in[18];
    const float* alpha = (const float*)d_in[19];
    const float* beta  = (const float*)d_in[20];
    const float* wpf = (const float*)d_in[21];
    const float* wpb = (const float*)d_in[22];
    const float* bias_pool = (const float*)d_in[23];
    const float* w1 = (const float*)d_in[24];
    const float* att_w = (const float*)d_in[25];
    const float* att_b = (const float*)d_in[26];
    float* out = (float*)d_out;

    float* ws = (float*)d_ws;
    float* nv  = ws;                                   // B*N*E      = 524288
    float* xs1 = nv + (size_t)NB * NN * NE;            // B*N*C each = 2097152
    float* xs2 = xs1 + (size_t)NB * NN * NC;
    float* xb1 = xs2 + (size_t)NB * NN * NC;
    float* xb2 = xb1 + (size_t)NB * NN * NC;
    float* gfb = xb2 + (size_t)NB * NN * NC;           // [2][B][64] = 4096
    float* scb = gfb + 4096;                           // [2][B][N]  = 65536
    float* ppb = scb + (size_t)2 * NB * NN;            // [2][B][16][64] = 65536
    float* Wbuf = ppb + (size_t)2 * NB * 16 * 64;      // N*192*64   = 12582912

    const size_t base_elems = (size_t)NB * NN * NE + 4 * (size_t)NB * NN * NC + 4096;
    const size_t attn_elems = (size_t)2 * NB * NN + (size_t)2 * NB * 16 * 64;
    const size_t w_elems = (size_t)NN * 192 * 64;
    const size_t need_bytes = (base_elems + attn_elems + w_elems) * sizeof(float);

    hipLaunchKernelGGL(nv_kernel, dim3(NB * NN / 4), dim3(256), 0, stream,
                       x, emb0, speed, occupy, fw1, fb1, fw2, fb2, fw3, fb3,
                       gw1, gb1, gw2, gb2, gw3, gb3, nv);
    dim3 gd(NN / 64, NB);
    hipLaunchKernelGGL(diffuse_kernel, gd, dim3(256), 0, stream, nv, x, xs1);
    hipLaunchKernelGGL(diffuse_kernel, gd, dim3(256), 0, stream, nv, xs1, xs2);
    hipLaunchKernelGGL(diffuse_kernel, gd, dim3(256), 0, stream, nv, xs2, xb1);
    hipLaunchKernelGGL(diffuse_kernel, gd, dim3(256), 0, stream, nv, xb1, xb2);

    if (ws_size >= need_bytes) {
        // parallel attention pool
        hipLaunchKernelGGL(scores_kernel, dim3(2 * NB * NN / 4), dim3(256), 0, stream,
                           x, xs1, xs2, xb1, xb2, att_w, att_b, scb);
        hipLaunchKernelGGL(softmax_kernel, dim3(2 * NB), dim3(256), 0, stream, scb);
        hipLaunchKernelGGL(poolpart_kernel, dim3(16, NB, 2), dim3(256), 0, stream,
                           x, xs1, xs2, xb1, xb2, scb, ppb);
        hipLaunchKernelGGL(poolfin_kernel, dim3(2 * NB), dim3(256), 0, stream, ppb, w1, gfb);
        // forward pass: out = alpha*d1 + bias + gf + gf1
        hipLaunchKernelGGL(wbuild_kernel, dim3(192), dim3(256), 0, stream, emb1, wpf, Wbuf);
        hipLaunchKernelGGL(apply_kernel, dim3(NN), dim3(256), 0, stream,
                           Wbuf, emb1, bias_pool, x, xs1, xs2, gfb, alpha, out, 0);
        // backward pass: out += beta*d2
        hipLaunchKernelGGL(wbuild_kernel, dim3(192), dim3(256), 0, stream, emb1, wpb, Wbuf);
        hipLaunchKernelGGL(apply_kernel, dim3(NN), dim3(256), 0, stream,
                           Wbuf, emb1, bias_pool, xs2, xb1, xb2, gfb, beta, out, 1);
    } else {
        hipLaunchKernelGGL(attnpool_kernel, dim3(NB, 2), dim3(256), 0, stream,
                           x, xs1, xs2, xs2, xb1, xb2, att_w, att_b, w1, gfb);
        hipLaunchKernelGGL(final_kernel, dim3(NN), dim3(256), 0, stream,
                           emb1, wpf, wpb, bias_pool, x, xs1, xs2, xb1, xb2, gfb, alpha, beta, out);
    }
}

// Round 4
// 382.582 us; speedup vs baseline: 8.2386x; 1.4732x over previous
//
#include <hip/hip_runtime.h>
#include <cmath>

#define NB 32
#define NN 1024
#define NC 64
#define NE 16

typedef _Float16 f16;
typedef __attribute__((ext_vector_type(2))) _Float16 f16x2;
typedef __attribute__((ext_vector_type(8))) _Float16 f16x8;
typedef __attribute__((ext_vector_type(16))) float f32x16;

#define NVSTR 24   // f16 per row: 16 data + 8 pad (48 B, 16B-aligned rows)
#define SSTR  40   // 32 data + 8 pad (80 B) -> S u16 writes hit disjoint bank halves
#define XSTR  40

__device__ __forceinline__ float sigm(float v) { return 1.0f / (1.0f + expf(-v)); }
__device__ __forceinline__ float lrelu(float v) { return v > 0.0f ? v : 0.01f * v; }

// ---------------- Kernel 1: nv = tanh(tanh(tanh(emb0*filt)*f1)*f2) ----------------
__global__ __launch_bounds__(256) void nv_kernel(
    const float* __restrict__ x, const float* __restrict__ emb0,
    const float* __restrict__ speed, const float* __restrict__ occupy,
    const float* __restrict__ fw1, const float* __restrict__ fb1,
    const float* __restrict__ fw2, const float* __restrict__ fb2,
    const float* __restrict__ fw3, const float* __restrict__ fb3,
    const float* __restrict__ gw1, const float* __restrict__ gb1,
    const float* __restrict__ gw2, const float* __restrict__ gb2,
    const float* __restrict__ gw3, const float* __restrict__ gb3,
    float* __restrict__ nv_out)
{
    const int sub = threadIdx.x >> 6;
    const int lt = threadIdx.x & 63;
    const int row = blockIdx.x * 4 + sub;   // b*N + n

    __shared__ float xr[4][64];
    __shared__ float h1[4][16];
    __shared__ float h2[4][2];
    __shared__ float g1[4][16];
    __shared__ float g2a[4][2];
    __shared__ float g2b[4][2];
    __shared__ float f1s[4][16];

    xr[sub][lt] = x[(size_t)row * 64 + lt];
    if (lt < 16) g1[sub][lt] = sigm(speed[row] * gw1[lt] + gb1[lt]);
    __syncthreads();
    if (lt < 16) {
        float s = fb1[lt];
        #pragma unroll
        for (int i = 0; i < 64; ++i) s += xr[sub][i] * fw1[lt * 64 + i];
        h1[sub][lt] = sigm(s);
    }
    __syncthreads();
    if (lt < 2) {
        float s = fb2[lt];
        #pragma unroll
        for (int i = 0; i < 16; ++i) s += h1[sub][i] * fw2[lt * 16 + i];
        h2[sub][lt] = sigm(s);
        float s2 = gb2[lt];
        #pragma unroll
        for (int i = 0; i < 16; ++i) s2 += g1[sub][i] * gw2[lt * 16 + i];
        g2a[sub][lt] = sigm(s2);
    }
    __syncthreads();
    if (lt < 16) {
        f1s[sub][lt] = g2a[sub][0] * gw3[lt * 2] + g2a[sub][1] * gw3[lt * 2 + 1] + gb3[lt];
        g1[sub][lt] = sigm(occupy[row] * gw1[lt] + gb1[lt]);
    }
    __syncthreads();
    if (lt < 2) {
        float s2 = gb2[lt];
        #pragma unroll
        for (int i = 0; i < 16; ++i) s2 += g1[sub][i] * gw2[lt * 16 + i];
        g2b[sub][lt] = sigm(s2);
    }
    __syncthreads();
    if (lt < 16) {
        float f2 = g2b[sub][0] * gw3[lt * 2] + g2b[sub][1] * gw3[lt * 2 + 1] + gb3[lt];
        float filt = h2[sub][0] * fw3[lt * 2] + h2[sub][1] * fw3[lt * 2 + 1] + fb3[lt];
        float v = tanhf(emb0[(size_t)row * 16 + lt] * filt);
        v = tanhf(v * f1s[sub][lt]);
        v = tanhf(v * f2);
        nv_out[(size_t)row * 16 + lt] = v;
    }
}

// ------- Kernel 2 (MFMA): y = LeakyReLU(S x), S-tile = relu(nv nv^T) via MFMA, f16 split -------
// grid (NB, 8): batch on x (XCD-local: id%8 = b%8), m-block on y. 256 thr = 4 waves.
// Wave w: y-tile rows (w&1)*64 + rb*32, cols (w>>1)*32; S-gen rows w*32.
__global__ __launch_bounds__(256) void diffuse_mfma_kernel(
    const float* __restrict__ nv, const float* __restrict__ xin,
    float* __restrict__ yout)
{
    const int b = blockIdx.x;
    const int m0 = blockIdx.y * 128;
    const int t = threadIdx.x;
    const int l = t & 63;
    const int w = t >> 6;
    const int g = l >> 5;
    const int l31 = l & 31;

    __shared__ __align__(16) f16 nvA_h[128 * NVSTR], nvA_l[128 * NVSTR];
    __shared__ __align__(16) f16 nvB_h[2][32 * NVSTR], nvB_l[2][32 * NVSTR];
    __shared__ __align__(16) f16 xT_h[2][64 * XSTR], xT_l[2][64 * XSTR];
    __shared__ __align__(16) f16 S_h[128 * SSTR], S_l[128 * SSTR];

    // ---- prologue: stage nvA rows m0..m0+128 (f16 hi/lo, k-contiguous) ----
    {
        int row = t >> 1, e0 = (t & 1) * 8;
        const float* src = nv + ((size_t)b * NN + m0 + row) * NE + e0;
        #pragma unroll
        for (int q = 0; q < 4; ++q) {
            float v0 = src[2 * q], v1 = src[2 * q + 1];
            f16 h0 = (f16)v0, h1 = (f16)v1;
            f16 lo0 = (f16)(v0 - (float)h0), lo1 = (f16)(v1 - (float)h1);
            f16x2 ph; ph[0] = h0; ph[1] = h1;
            f16x2 pl; pl[0] = lo0; pl[1] = lo1;
            *(f16x2*)&nvA_h[row * NVSTR + e0 + 2 * q] = ph;
            *(f16x2*)&nvA_l[row * NVSTR + e0 + 2 * q] = pl;
        }
    }

#define STAGE(n0v, bufv) do { \
    if (t < 64) { \
        int nl_ = t >> 1, e0_ = (t & 1) * 8; \
        const float* s_ = nv + ((size_t)b * NN + (n0v) + nl_) * NE + e0_; \
        _Pragma("unroll") \
        for (int q = 0; q < 4; ++q) { \
            float v0 = s_[2 * q], v1 = s_[2 * q + 1]; \
            f16 h0 = (f16)v0, h1 = (f16)v1; \
            f16 lo0 = (f16)(v0 - (float)h0), lo1 = (f16)(v1 - (float)h1); \
            f16x2 ph; ph[0] = h0; ph[1] = h1; \
            f16x2 pl; pl[0] = lo0; pl[1] = lo1; \
            *(f16x2*)&nvB_h[bufv][nl_ * NVSTR + e0_ + 2 * q] = ph; \
            *(f16x2*)&nvB_l[bufv][nl_ * NVSTR + e0_ + 2 * q] = pl; \
        } \
    } \
    { \
        int k_ = t >> 3, c0_ = t & 7; \
        const float* s_ = xin + ((size_t)b * NN + (n0v) + k_) * NC + c0_; \
        _Pragma("unroll") \
        for (int i = 0; i < 8; ++i) { \
            float v = s_[8 * i]; \
            f16 h = (f16)v; f16 lo = (f16)(v - (float)h); \
            int c_ = c0_ + 8 * i; \
            xT_h[bufv][c_ * XSTR + k_] = h; \
            xT_l[bufv][c_ * XSTR + k_] = lo; \
        } \
    } \
} while (0)

    STAGE(0, 0);
    __syncthreads();

    f32x16 acc0, acc1;
    #pragma unroll
    for (int r = 0; r < 16; ++r) { acc0[r] = 0.0f; acc1[r] = 0.0f; }

    const int mh = w & 1;
    const int cc = w >> 1;

    for (int s = 0; s < 32; ++s) {
        const int cur = s & 1;
        // ---- R1: S-gen (wave w: S rows w*32..w*32+32, cols = this K-window) ----
        {
            f16x8 Ah = *(const f16x8*)&nvA_h[(w * 32 + l31) * NVSTR + g * 8];
            f16x8 Al = *(const f16x8*)&nvA_l[(w * 32 + l31) * NVSTR + g * 8];
            f16x8 Bh = *(const f16x8*)&nvB_h[cur][l31 * NVSTR + g * 8];
            f16x8 Bl = *(const f16x8*)&nvB_l[cur][l31 * NVSTR + g * 8];
            f32x16 sa;
            #pragma unroll
            for (int r = 0; r < 16; ++r) sa[r] = 0.0f;
            sa = __builtin_amdgcn_mfma_f32_32x32x16_f16(Al, Bh, sa, 0, 0, 0);
            sa = __builtin_amdgcn_mfma_f32_32x32x16_f16(Ah, Bl, sa, 0, 0, 0);
            sa = __builtin_amdgcn_mfma_f32_32x32x16_f16(Ah, Bh, sa, 0, 0, 0);
            #pragma unroll
            for (int r = 0; r < 16; ++r) {
                float vv = fmaxf(sa[r], 0.0f);
                f16 h = (f16)vv; f16 lo = (f16)(vv - (float)h);
                int row = w * 32 + (r & 3) + 8 * (r >> 2) + 4 * g;
                S_h[row * SSTR + l31] = h;
                S_l[row * SSTR + l31] = lo;
            }
        }
        if (s + 1 < 32) STAGE((s + 1) * 32, cur ^ 1);
        __syncthreads();
        // ---- R2: y += S * x  (A = S rows, B = xT cols) ----
        #pragma unroll
        for (int ch = 0; ch < 2; ++ch) {
            f16x8 Bh = *(const f16x8*)&xT_h[cur][(cc * 32 + l31) * XSTR + ch * 16 + g * 8];
            f16x8 Bl = *(const f16x8*)&xT_l[cur][(cc * 32 + l31) * XSTR + ch * 16 + g * 8];
            {
                int sr = (mh * 64 + l31) * SSTR + ch * 16 + g * 8;
                f16x8 Ah = *(const f16x8*)&S_h[sr];
                f16x8 Al = *(const f16x8*)&S_l[sr];
                acc0 = __builtin_amdgcn_mfma_f32_32x32x16_f16(Al, Bh, acc0, 0, 0, 0);
                acc0 = __builtin_amdgcn_mfma_f32_32x32x16_f16(Ah, Bl, acc0, 0, 0, 0);
                acc0 = __builtin_amdgcn_mfma_f32_32x32x16_f16(Ah, Bh, acc0, 0, 0, 0);
            }
            {
                int sr = (mh * 64 + 32 + l31) * SSTR + ch * 16 + g * 8;
                f16x8 Ah = *(const f16x8*)&S_h[sr];
                f16x8 Al = *(const f16x8*)&S_l[sr];
                acc1 = __builtin_amdgcn_mfma_f32_32x32x16_f16(Al, Bh, acc1, 0, 0, 0);
                acc1 = __builtin_amdgcn_mfma_f32_32x32x16_f16(Ah, Bl, acc1, 0, 0, 0);
                acc1 = __builtin_amdgcn_mfma_f32_32x32x16_f16(Ah, Bh, acc1, 0, 0, 0);
            }
        }
        __syncthreads();
    }
#undef STAGE

    // ---- epilogue: lrelu + store ----
    const int colg = cc * 32 + l31;
    #pragma unroll
    for (int r = 0; r < 16; ++r) {
        int row0 = m0 + mh * 64 + (r & 3) + 8 * (r >> 2) + 4 * g;
        float v0 = lrelu(acc0[r]);
        float v1 = lrelu(acc1[r]);
        yout[((size_t)b * NN + row0) * NC + colg] = v0;
        yout[((size_t)b * NN + row0 + 32) * NC + colg] = v1;
    }
}

// ======= Attention pool, stage A: per-row scores (one wave per row) =======
__global__ __launch_bounds__(256) void scores_kernel(
    const float* __restrict__ x, const float* __restrict__ xs1, const float* __restrict__ xs2,
    const float* __restrict__ xb1, const float* __restrict__ xb2,
    const float* __restrict__ att_w, const float* __restrict__ att_b,
    float* __restrict__ sc)
{
    const int lane = threadIdx.x & 63;
    const int w = threadIdx.x >> 6;
    const int r = blockIdx.x * 4 + w;
    const int which = r >= NB * NN;
    const int rr = r - which * NB * NN;

    const float* p0 = which ? xs2 : x;
    const float* p1 = which ? xb1 : xs1;
    const float* p2 = which ? xb2 : xs2;

    size_t idx = (size_t)rr * NC + lane;
    float nf = (p0[idx] + p1[idx] + p2[idx]) * (1.0f / 3.0f);
    float v = nf * att_w[lane];
    #pragma unroll
    for (int off = 32; off > 0; off >>= 1) v += __shfl_xor(v, off);
    if (lane == 0) sc[r] = v + att_b[0];
}

// ======= Stage B: softmax over the 1024 nodes of one (which,b) =======
__global__ __launch_bounds__(256) void softmax_kernel(float* __restrict__ sc)
{
    const int wb = blockIdx.x;
    const int t = threadIdx.x;
    const int lane = t & 63;
    const int w = t >> 6;
    float* p = sc + (size_t)wb * NN;

    __shared__ float red[4];
    float4 v = reinterpret_cast<const float4*>(p)[t];
    float m = fmaxf(fmaxf(v.x, v.y), fmaxf(v.z, v.w));
    #pragma unroll
    for (int off = 32; off > 0; off >>= 1) m = fmaxf(m, __shfl_xor(m, off));
    if (lane == 0) red[w] = m;
    __syncthreads();
    m = fmaxf(fmaxf(red[0], red[1]), fmaxf(red[2], red[3]));
    __syncthreads();
    v.x = expf(v.x - m); v.y = expf(v.y - m); v.z = expf(v.z - m); v.w = expf(v.w - m);
    float s = v.x + v.y + v.z + v.w;
    #pragma unroll
    for (int off = 32; off > 0; off >>= 1) s += __shfl_xor(s, off);
    if (lane == 0) red[w] = s;
    __syncthreads();
    const float inv = 1.0f / (red[0] + red[1] + red[2] + red[3]);
    v.x *= inv; v.y *= inv; v.z *= inv; v.w *= inv;
    reinterpret_cast<float4*>(p)[t] = v;
}

// ======= Stage C: partial weighted sums over 64-node chunks =======
__global__ __launch_bounds__(256) void poolpart_kernel(
    const float* __restrict__ x, const float* __restrict__ xs1, const float* __restrict__ xs2,
    const float* __restrict__ xb1, const float* __restrict__ xb2,
    const float* __restrict__ sc, float* __restrict__ partial)
{
    const int chunk = blockIdx.x;
    const int b = blockIdx.y;
    const int which = blockIdx.z;
    const int lane = threadIdx.x & 63;
    const int w = threadIdx.x >> 6;

    const float* p0 = which ? xs2 : x;
    const float* p1 = which ? xb1 : xs1;
    const float* p2 = which ? xb2 : xs2;

    const int n0 = chunk * 64;
    const size_t base = (size_t)b * NN;
    float acc = 0.0f;
    for (int j = w; j < 64; j += 4) {
        int n = n0 + j;
        size_t idx = (base + n) * NC + lane;
        float nf = (p0[idx] + p1[idx] + p2[idx]) * (1.0f / 3.0f);
        acc += nf * sc[((size_t)which * NB + b) * NN + n];
    }
    __shared__ float red[4][64];
    red[w][lane] = acc;
    __syncthreads();
    if (w == 0) {
        float s = red[0][lane] + red[1][lane] + red[2][lane] + red[3][lane];
        partial[(((size_t)which * NB + b) * 16 + chunk) * 64 + lane] = s;
    }
}

// ======= Stage D: reduce partials + multiply by weights1 =======
__global__ __launch_bounds__(256) void poolfin_kernel(
    const float* __restrict__ partial, const float* __restrict__ w1,
    float* __restrict__ gf_out)
{
    const int wb = blockIdx.x;
    const int t = threadIdx.x;
    const int lane = t & 63;
    const int w = t >> 6;

    __shared__ float red[4][64];
    __shared__ float gfin[64];
    float acc = 0.0f;
    #pragma unroll
    for (int r = w; r < 16; r += 4)
        acc += partial[((size_t)wb * 16 + r) * 64 + lane];
    red[w][lane] = acc;
    __syncthreads();
    if (w == 0) gfin[lane] = red[0][lane] + red[1][lane] + red[2][lane] + red[3][lane];
    __syncthreads();
    if (w == 0) {
        float s = 0.0f;
        #pragma unroll
        for (int c = 0; c < 64; ++c) s += gfin[c] * w1[c * 64 + lane];
        gf_out[(size_t)wb * 64 + lane] = s;
    }
}

// ------- Kernel 4a: W[n][ki][o] = sum_e emb1[n,e] * pool[e][ki][o] (grid 192 x 4) -------
__global__ __launch_bounds__(256) void wbuild_kernel(
    const float* __restrict__ emb1, const float* __restrict__ pool,
    float* __restrict__ W)
{
    const int ki = blockIdx.x;            // 0..191
    const int chunk = blockIdx.y;         // 0..3
    const int t = threadIdx.x;
    const int o = t & 63;

    __shared__ float slab[16][64];
    __shared__ float eloc[256][16];

    for (int idx = t; idx < 1024; idx += 256)
        slab[idx >> 6][idx & 63] = pool[((size_t)(idx >> 6) * 192 + ki) * 64 + (idx & 63)];
    for (int idx = t; idx < 4096; idx += 256)
        eloc[idx >> 4][idx & 15] = emb1[((size_t)chunk * 256 + (idx >> 4)) * 16 + (idx & 15)];
    __syncthreads();
    for (int nl = t >> 6; nl < 256; nl += 4) {
        float s = 0.0f;
        #pragma unroll
        for (int e = 0; e < 16; ++e) s += eloc[nl][e] * slab[e][o];
        W[((size_t)(chunk * 256 + nl) * 192 + ki) * 64 + o] = s;
    }
}

// ------- Kernel 4b: per node n, out[b,o] (pass0: = a*d + bias + gf; pass1: += b*d) -------
__global__ __launch_bounds__(256) void apply_kernel(
    const float* __restrict__ W, const float* __restrict__ emb1,
    const float* __restrict__ bias_pool,
    const float* __restrict__ s0, const float* __restrict__ s1, const float* __restrict__ s2,
    const float* __restrict__ gf, const float* __restrict__ scale,
    float* __restrict__ out, int pass)
{
    const int n = blockIdx.x;
    const int t = threadIdx.x;
    const int o = t & 63;
    const int bg = t >> 6;

    __shared__ float Wn[192][64];
    __shared__ float Xs[3][32][64];
    __shared__ float e1s[16];

    if (t < 16) e1s[t] = emb1[n * 16 + t];
    {
        const float4* src = reinterpret_cast<const float4*>(W + (size_t)n * 192 * 64);
        float4* dst = reinterpret_cast<float4*>(&Wn[0][0]);
        #pragma unroll
        for (int r = 0; r < 12; ++r) dst[t + 256 * r] = src[t + 256 * r];
    }
    const float* srcs[3] = {s0, s1, s2};
    #pragma unroll
    for (int k = 0; k < 3; ++k) {
        const float* sp = srcs[k];
        #pragma unroll
        for (int r = 0; r < 2; ++r) {
            int idx = t + 256 * r;
            int b = idx >> 4, i4 = idx & 15;
            reinterpret_cast<float4*>(&Xs[k][b][0])[i4] =
                reinterpret_cast<const float4*>(sp + ((size_t)b * NN + n) * NC)[i4];
        }
    }
    __syncthreads();

    float acc[8] = {};
    #pragma unroll 4
    for (int ki = 0; ki < 192; ++ki) {
        float wv = Wn[ki][o];
        int k = ki >> 6, i = ki & 63;
        #pragma unroll
        for (int j = 0; j < 8; ++j) acc[j] += Xs[k][bg * 8 + j][i] * wv;
    }

    const float sc = scale[0];
    if (pass == 0) {
        float bias_o = 0.0f;
        #pragma unroll
        for (int e = 0; e < 16; ++e) bias_o += e1s[e] * bias_pool[e * 64 + o];
        #pragma unroll
        for (int j = 0; j < 8; ++j) {
            int b = bg * 8 + j;
            float g = gf[(size_t)b * 64 + o] + gf[((size_t)NB + b) * 64 + o];
            out[((size_t)b * NN + n) * NC + o] = sc * acc[j] + bias_o + g;
        }
    } else {
        #pragma unroll
        for (int j = 0; j < 8; ++j) {
            int b = bg * 8 + j;
            out[((size_t)b * NN + n) * NC + o] += sc * acc[j];
        }
    }
}

// ------- Fallback final kernel (ws too small) -------
__global__ __launch_bounds__(256) void final_kernel(
    const float* __restrict__ emb1,
    const float* __restrict__ wpf, const float* __restrict__ wpb,
    const float* __restrict__ bias_pool,
    const float* __restrict__ x, const float* __restrict__ xs1, const float* __restrict__ xs2,
    const float* __restrict__ xb1, const float* __restrict__ xb2,
    const float* __restrict__ gf, const float* __restrict__ alpha, const float* __restrict__ beta,
    float* __restrict__ out)
{
    const int n = blockIdx.x;
    const int t = threadIdx.x;
    const int o = t & 63;
    const int bg = t >> 6;

    __shared__ float Wk[64][64];
    __shared__ float xk[32][64];
    __shared__ float e1[16];
    if (t < 16) e1[t] = emb1[n * 16 + t];

    float acc[2][8];
    #pragma unroll
    for (int d = 0; d < 2; ++d)
        #pragma unroll
        for (int j = 0; j < 8; ++j) acc[d][j] = 0.0f;

    const float* srcs[2][3] = {{x, xs1, xs2}, {xs2, xb1, xb2}};

    #pragma unroll
    for (int dir = 0; dir < 2; ++dir) {
        const float* wp = dir ? wpb : wpf;
        #pragma unroll
        for (int k = 0; k < 3; ++k) {
            __syncthreads();
            for (int idx = t; idx < 4096; idx += 256) {
                int i = idx >> 6, oo = idx & 63;
                float s = 0.0f;
                #pragma unroll
                for (int e = 0; e < 16; ++e) s += e1[e] * wp[(((size_t)e * 3 + k) * 64 + i) * 64 + oo];
                Wk[i][oo] = s;
            }
            const float* src = srcs[dir][k];
            for (int idx = t; idx < 2048; idx += 256) {
                int bb = idx >> 6, ii = idx & 63;
                xk[bb][ii] = src[((size_t)bb * NN + n) * NC + ii];
            }
            __syncthreads();
            #pragma unroll
            for (int j = 0; j < 8; ++j) {
                int bb = bg * 8 + j;
                float s = 0.0f;
                #pragma unroll
                for (int i = 0; i < 64; i += 4) {
                    float4 xv = *reinterpret_cast<const float4*>(&xk[bb][i]);
                    s += xv.x * Wk[i][o] + xv.y * Wk[i + 1][o] + xv.z * Wk[i + 2][o] + xv.w * Wk[i + 3][o];
                }
                acc[dir][j] += s;
            }
        }
    }

    float bias_o = 0.0f;
    #pragma unroll
    for (int e = 0; e < 16; ++e) bias_o += e1[e] * bias_pool[e * 64 + o];
    const float al = alpha[0], be = beta[0];
    #pragma unroll
    for (int j = 0; j < 8; ++j) {
        int bb = bg * 8 + j;
        float g = gf[(size_t)bb * 64 + o] + gf[((size_t)NB + bb) * 64 + o];
        out[((size_t)bb * NN + n) * NC + o] = al * acc[0][j] + be * acc[1][j] + bias_o + g;
    }
}

// ------- Fallback attnpool (ws too small) -------
__global__ __launch_bounds__(256) void attnpool_kernel(
    const float* __restrict__ a0, const float* __restrict__ a1, const float* __restrict__ a2,
    const float* __restrict__ c0, const float* __restrict__ c1, const float* __restrict__ c2,
    const float* __restrict__ att_w, const float* __restrict__ att_b,
    const float* __restrict__ w1, float* __restrict__ gf_out)
{
    const int b = blockIdx.x;
    const int which = blockIdx.y;
    const float* p0 = which ? c0 : a0;
    const float* p1 = which ? c1 : a1;
    const float* p2 = which ? c2 : a2;
    const int t = threadIdx.x;
    const int lane = t & 63;
    const int w = t >> 6;

    __shared__ float sc[NN];
    __shared__ float red[4];
    __shared__ float gfp[4][64];
    __shared__ float gfin[64];

    const float aw = att_w[lane];
    const size_t base = (size_t)b * NN * NC;

    for (int n = w; n < NN; n += 4) {
        size_t idx = base + (size_t)n * NC + lane;
        float nf = (p0[idx] + p1[idx] + p2[idx]) * (1.0f / 3.0f);
        float v = nf * aw;
        #pragma unroll
        for (int off = 32; off > 0; off >>= 1) v += __shfl_xor(v, off);
        if (lane == 0) sc[n] = v + att_b[0];
    }
    __syncthreads();
    float m = -INFINITY;
    for (int i = t; i < NN; i += 256) m = fmaxf(m, sc[i]);
    #pragma unroll
    for (int off = 32; off > 0; off >>= 1) m = fmaxf(m, __shfl_xor(m, off));
    if (lane == 0) red[w] = m;
    __syncthreads();
    m = fmaxf(fmaxf(red[0], red[1]), fmaxf(red[2], red[3]));
    __syncthreads();
    float s = 0.0f;
    for (int i = t; i < NN; i += 256) { float e = expf(sc[i] - m); sc[i] = e; s += e; }
    #pragma unroll
    for (int off = 32; off > 0; off >>= 1) s += __shfl_xor(s, off);
    if (lane == 0) red[w] = s;
    __syncthreads();
    const float inv_denom = 1.0f / (red[0] + red[1] + red[2] + red[3]);

    float acc = 0.0f;
    for (int n = w; n < NN; n += 4) {
        size_t idx = base + (size_t)n * NC + lane;
        float nf = (p0[idx] + p1[idx] + p2[idx]) * (1.0f / 3.0f);
        acc += nf * sc[n];
    }
    gfp[w][lane] = acc;
    __syncthreads();
    if (w == 0) gfin[lane] = (gfp[0][lane] + gfp[1][lane] + gfp[2][lane] + gfp[3][lane]) * inv_denom;
    __syncthreads();
    if (w == 0) {
        float s2 = 0.0f;
        #pragma unroll
        for (int c = 0; c < 64; ++c) s2 += gfin[c] * w1[c * 64 + lane];
        gf_out[((size_t)which * NB + b) * 64 + lane] = s2;
    }
}

extern "C" void kernel_launch(void* const* d_in, const int* in_sizes, int n_in,
                              void* d_out, int out_size, void* d_ws, size_t ws_size,
                              hipStream_t stream)
{
    const float* x      = (const float*)d_in[0];
    const float* emb0   = (const float*)d_in[1];
    const float* emb1   = (const float*)d_in[2];
    const float* speed  = (const float*)d_in[5];
    const float* occupy = (const float*)d_in[6];
    const float* fw1 = (const float*)d_in[7];
    const float* fb1 = (const float*)d_in[8];
    const float* fw2 = (const float*)d_in[9];
    const float* fb2 = (const float*)d_in[10];
    const float* fw3 = (const float*)d_in[11];
    const float* fb3 = (const float*)d_in[12];
    const float* gw1 = (const float*)d_in[13];
    const float* gb1 = (const float*)d_in[14];
    const float* gw2 = (const float*)d_in[15];
    const float* gb2 = (const float*)d_in[16];
    const float* gw3 = (const float*)d_in[17];
    const float* gb3 = (const float*)d_in[18];
    const float* alpha = (const float*)d_in[19];
    const float* beta  = (const float*)d_in[20];
    const float* wpf = (const float*)d_in[21];
    const float* wpb = (const float*)d_in[22];
    const float* bias_pool = (const float*)d_in[23];
    const float* w1 = (const float*)d_in[24];
    const float* att_w = (const float*)d_in[25];
    const float* att_b = (const float*)d_in[26];
    float* out = (float*)d_out;

    float* ws = (float*)d_ws;
    float* nv  = ws;                                   // B*N*E
    float* xs1 = nv + (size_t)NB * NN * NE;            // B*N*C each
    float* xs2 = xs1 + (size_t)NB * NN * NC;
    float* xb1 = xs2 + (size_t)NB * NN * NC;
    float* xb2 = xb1 + (size_t)NB * NN * NC;
    float* gfb = xb2 + (size_t)NB * NN * NC;           // [2][B][64]
    float* scb = gfb + 4096;                           // [2][B][N]
    float* ppb = scb + (size_t)2 * NB * NN;            // [2][B][16][64]
    float* Wbuf = ppb + (size_t)2 * NB * 16 * 64;      // N*192*64

    const size_t base_elems = (size_t)NB * NN * NE + 4 * (size_t)NB * NN * NC + 4096;
    const size_t attn_elems = (size_t)2 * NB * NN + (size_t)2 * NB * 16 * 64;
    const size_t w_elems = (size_t)NN * 192 * 64;
    const size_t need_bytes = (base_elems + attn_elems + w_elems) * sizeof(float);

    hipLaunchKernelGGL(nv_kernel, dim3(NB * NN / 4), dim3(256), 0, stream,
                       x, emb0, speed, occupy, fw1, fb1, fw2, fb2, fw3, fb3,
                       gw1, gb1, gw2, gb2, gw3, gb3, nv);
    dim3 gd(NB, NN / 128);
    hipLaunchKernelGGL(diffuse_mfma_kernel, gd, dim3(256), 0, stream, nv, x, xs1);
    hipLaunchKernelGGL(diffuse_mfma_kernel, gd, dim3(256), 0, stream, nv, xs1, xs2);
    hipLaunchKernelGGL(diffuse_mfma_kernel, gd, dim3(256), 0, stream, nv, xs2, xb1);
    hipLaunchKernelGGL(diffuse_mfma_kernel, gd, dim3(256), 0, stream, nv, xb1, xb2);

    if (ws_size >= need_bytes) {
        hipLaunchKernelGGL(scores_kernel, dim3(2 * NB * NN / 4), dim3(256), 0, stream,
                           x, xs1, xs2, xb1, xb2, att_w, att_b, scb);
        hipLaunchKernelGGL(softmax_kernel, dim3(2 * NB), dim3(256), 0, stream, scb);
        hipLaunchKernelGGL(poolpart_kernel, dim3(16, NB, 2), dim3(256), 0, stream,
                           x, xs1, xs2, xb1, xb2, scb, ppb);
        hipLaunchKernelGGL(poolfin_kernel, dim3(2 * NB), dim3(256), 0, stream, ppb, w1, gfb);
        hipLaunchKernelGGL(wbuild_kernel, dim3(192, 4), dim3(256), 0, stream, emb1, wpf, Wbuf);
        hipLaunchKernelGGL(apply_kernel, dim3(NN), dim3(256), 0, stream,
                           Wbuf, emb1, bias_pool, x, xs1, xs2, gfb, alpha, out, 0);
        hipLaunchKernelGGL(wbuild_kernel, dim3(192, 4), dim3(256), 0, stream, emb1, wpb, Wbuf);
        hipLaunchKernelGGL(apply_kernel, dim3(NN), dim3(256), 0, stream,
                           Wbuf, emb1, bias_pool, xs2, xb1, xb2, gfb, beta, out, 1);
    } else {
        hipLaunchKernelGGL(attnpool_kernel, dim3(NB, 2), dim3(256), 0, stream,
                           x, xs1, xs2, xs2, xb1, xb2, att_w, att_b, w1, gfb);
        hipLaunchKernelGGL(final_kernel, dim3(NN), dim3(256), 0, stream,
                           emb1, wpf, wpb, bias_pool, x, xs1, xs2, xb1, xb2, gfb, alpha, beta, out);
    }
}

// Round 5
// 328.814 us; speedup vs baseline: 9.5858x; 1.1635x over previous
//
#include <hip/hip_runtime.h>
#include <cmath>

#define NB 32
#define NN 1024
#define NC 64
#define NE 16

typedef _Float16 f16;
typedef __attribute__((ext_vector_type(2))) _Float16 f16x2;
typedef __attribute__((ext_vector_type(8))) _Float16 f16x8;
typedef __attribute__((ext_vector_type(16))) float f32x16;

#define NVSTR 24   // f16 per row: 16 data + 8 pad
#define SSTR  40
#define XSTR  40
#define ASTR  40

__device__ __forceinline__ float sigm(float v) { return 1.0f / (1.0f + expf(-v)); }
__device__ __forceinline__ float lrelu(float v) { return v > 0.0f ? v : 0.01f * v; }

// ---------------- Kernel 1: nv = tanh(tanh(tanh(emb0*filt)*f1)*f2) ----------------
__global__ __launch_bounds__(256) void nv_kernel(
    const float* __restrict__ x, const float* __restrict__ emb0,
    const float* __restrict__ speed, const float* __restrict__ occupy,
    const float* __restrict__ fw1, const float* __restrict__ fb1,
    const float* __restrict__ fw2, const float* __restrict__ fb2,
    const float* __restrict__ fw3, const float* __restrict__ fb3,
    const float* __restrict__ gw1, const float* __restrict__ gb1,
    const float* __restrict__ gw2, const float* __restrict__ gb2,
    const float* __restrict__ gw3, const float* __restrict__ gb3,
    float* __restrict__ nv_out)
{
    const int sub = threadIdx.x >> 6;
    const int lt = threadIdx.x & 63;
    const int row = blockIdx.x * 4 + sub;   // b*N + n

    __shared__ float xr[4][64];
    __shared__ float h1[4][16];
    __shared__ float h2[4][2];
    __shared__ float g1[4][16];
    __shared__ float g2a[4][2];
    __shared__ float g2b[4][2];
    __shared__ float f1s[4][16];

    xr[sub][lt] = x[(size_t)row * 64 + lt];
    if (lt < 16) g1[sub][lt] = sigm(speed[row] * gw1[lt] + gb1[lt]);
    __syncthreads();
    if (lt < 16) {
        float s = fb1[lt];
        #pragma unroll
        for (int i = 0; i < 64; ++i) s += xr[sub][i] * fw1[lt * 64 + i];
        h1[sub][lt] = sigm(s);
    }
    __syncthreads();
    if (lt < 2) {
        float s = fb2[lt];
        #pragma unroll
        for (int i = 0; i < 16; ++i) s += h1[sub][i] * fw2[lt * 16 + i];
        h2[sub][lt] = sigm(s);
        float s2 = gb2[lt];
        #pragma unroll
        for (int i = 0; i < 16; ++i) s2 += g1[sub][i] * gw2[lt * 16 + i];
        g2a[sub][lt] = sigm(s2);
    }
    __syncthreads();
    if (lt < 16) {
        f1s[sub][lt] = g2a[sub][0] * gw3[lt * 2] + g2a[sub][1] * gw3[lt * 2 + 1] + gb3[lt];
        g1[sub][lt] = sigm(occupy[row] * gw1[lt] + gb1[lt]);
    }
    __syncthreads();
    if (lt < 2) {
        float s2 = gb2[lt];
        #pragma unroll
        for (int i = 0; i < 16; ++i) s2 += g1[sub][i] * gw2[lt * 16 + i];
        g2b[sub][lt] = sigm(s2);
    }
    __syncthreads();
    if (lt < 16) {
        float f2 = g2b[sub][0] * gw3[lt * 2] + g2b[sub][1] * gw3[lt * 2 + 1] + gb3[lt];
        float filt = h2[sub][0] * fw3[lt * 2] + h2[sub][1] * fw3[lt * 2 + 1] + fb3[lt];
        float v = tanhf(emb0[(size_t)row * 16 + lt] * filt);
        v = tanhf(v * f1s[sub][lt]);
        v = tanhf(v * f2);
        nv_out[(size_t)row * 16 + lt] = v;
    }
}

// ------- sgen: materialize S = relu(nv nv^T) as split f16 planes Sh/Sl [b][m][n] -------
__global__ __launch_bounds__(256) void sgen_kernel(
    const float* __restrict__ nv, f16* __restrict__ Sh, f16* __restrict__ Sl)
{
    const int b = blockIdx.x;
    const int m0 = blockIdx.y * 128;
    const int t = threadIdx.x;
    const int l = t & 63;
    const int w = t >> 6;
    const int g = l >> 5;
    const int l31 = l & 31;

    __shared__ __align__(16) f16 nvA_h[128 * NVSTR], nvA_l[128 * NVSTR];
    __shared__ __align__(16) f16 nvB_h[128 * NVSTR], nvB_l[128 * NVSTR];

    {
        int row = t >> 1, e0 = (t & 1) * 8;
        const float* src = nv + ((size_t)b * NN + m0 + row) * NE + e0;
        #pragma unroll
        for (int q = 0; q < 4; ++q) {
            float v0 = src[2 * q], v1 = src[2 * q + 1];
            f16 h0 = (f16)v0, h1 = (f16)v1;
            f16 lo0 = (f16)(v0 - (float)h0), lo1 = (f16)(v1 - (float)h1);
            f16x2 ph; ph[0] = h0; ph[1] = h1;
            f16x2 pl; pl[0] = lo0; pl[1] = lo1;
            *(f16x2*)&nvA_h[row * NVSTR + e0 + 2 * q] = ph;
            *(f16x2*)&nvA_l[row * NVSTR + e0 + 2 * q] = pl;
        }
    }
    const size_t sbase = (size_t)b * NN * NN;
    for (int it = 0; it < 8; ++it) {
        __syncthreads();   // nvB free (prev compute done)
        {
            int row = t >> 1, e0 = (t & 1) * 8;
            const float* src = nv + ((size_t)b * NN + it * 128 + row) * NE + e0;
            #pragma unroll
            for (int q = 0; q < 4; ++q) {
                float v0 = src[2 * q], v1 = src[2 * q + 1];
                f16 h0 = (f16)v0, h1 = (f16)v1;
                f16 lo0 = (f16)(v0 - (float)h0), lo1 = (f16)(v1 - (float)h1);
                f16x2 ph; ph[0] = h0; ph[1] = h1;
                f16x2 pl; pl[0] = lo0; pl[1] = lo1;
                *(f16x2*)&nvB_h[row * NVSTR + e0 + 2 * q] = ph;
                *(f16x2*)&nvB_l[row * NVSTR + e0 + 2 * q] = pl;
            }
        }
        __syncthreads();
        f16x8 Ah = *(const f16x8*)&nvA_h[(w * 32 + l31) * NVSTR + g * 8];
        f16x8 Al = *(const f16x8*)&nvA_l[(w * 32 + l31) * NVSTR + g * 8];
        #pragma unroll
        for (int tile = 0; tile < 4; ++tile) {
            f16x8 Bh = *(const f16x8*)&nvB_h[(tile * 32 + l31) * NVSTR + g * 8];
            f16x8 Bl = *(const f16x8*)&nvB_l[(tile * 32 + l31) * NVSTR + g * 8];
            f32x16 sa;
            #pragma unroll
            for (int r = 0; r < 16; ++r) sa[r] = 0.0f;
            sa = __builtin_amdgcn_mfma_f32_32x32x16_f16(Al, Bh, sa, 0, 0, 0);
            sa = __builtin_amdgcn_mfma_f32_32x32x16_f16(Ah, Bl, sa, 0, 0, 0);
            sa = __builtin_amdgcn_mfma_f32_32x32x16_f16(Ah, Bh, sa, 0, 0, 0);
            const int n = it * 128 + tile * 32 + l31;
            #pragma unroll
            for (int r = 0; r < 16; ++r) {
                float vv = fmaxf(sa[r], 0.0f);
                f16 h = (f16)vv; f16 lo = (f16)(vv - (float)h);
                int m = m0 + w * 32 + (r & 3) + 8 * (r >> 2) + 4 * g;
                Sh[sbase + (size_t)m * NN + n] = h;
                Sl[sbase + (size_t)m * NN + n] = lo;
            }
        }
    }
}

// ------- diffuse2: y = lrelu(S x) reading materialized split S; M-tile 64, dbuf LDS -------
__global__ __launch_bounds__(256) void diffuse2_kernel(
    const f16* __restrict__ Sh, const f16* __restrict__ Sl,
    const float* __restrict__ xin, float* __restrict__ yout)
{
    const int b = blockIdx.x;
    const int m0 = blockIdx.y * 64;
    const int t = threadIdx.x;
    const int l = t & 63;
    const int g = l >> 5;
    const int l31 = l & 31;
    const int w = t >> 6;
    const int mh = w & 1;
    const int ch = w >> 1;

    __shared__ __align__(16) f16 As_h[2][64 * ASTR], As_l[2][64 * ASTR];
    __shared__ __align__(16) f16 Xs_h[2][64 * XSTR], Xs_l[2][64 * XSTR];

    const size_t sbase = (size_t)b * NN * NN + (size_t)m0 * NN;
    const int arow = t >> 2, akc = t & 3;
    const int xk = t >> 3, xc0 = t & 7;

#define D2STAGE(n0v, bufv) do { \
    *(f16x8*)&As_h[bufv][arow * ASTR + akc * 8] = \
        *(const f16x8*)&Sh[sbase + (size_t)arow * NN + (n0v) + akc * 8]; \
    *(f16x8*)&As_l[bufv][arow * ASTR + akc * 8] = \
        *(const f16x8*)&Sl[sbase + (size_t)arow * NN + (n0v) + akc * 8]; \
    { \
        const float* xs_ = xin + ((size_t)b * NN + (n0v) + xk) * NC + xc0; \
        _Pragma("unroll") \
        for (int i = 0; i < 8; ++i) { \
            float v = xs_[8 * i]; \
            f16 h = (f16)v; f16 lo = (f16)(v - (float)h); \
            int c_ = xc0 + 8 * i; \
            Xs_h[bufv][c_ * XSTR + xk] = h; \
            Xs_l[bufv][c_ * XSTR + xk] = lo; \
        } \
    } \
} while (0)

    D2STAGE(0, 0);
    f32x16 acc;
    #pragma unroll
    for (int r = 0; r < 16; ++r) acc[r] = 0.0f;
    __syncthreads();

    for (int s = 0; s < 32; ++s) {
        const int cur = s & 1;
        if (s + 1 < 32) D2STAGE((s + 1) * 32, cur ^ 1);
        #pragma unroll
        for (int ku = 0; ku < 2; ++ku) {
            f16x8 Bh = *(const f16x8*)&Xs_h[cur][(ch * 32 + l31) * XSTR + ku * 16 + g * 8];
            f16x8 Bl = *(const f16x8*)&Xs_l[cur][(ch * 32 + l31) * XSTR + ku * 16 + g * 8];
            f16x8 Aa = *(const f16x8*)&As_h[cur][(mh * 32 + l31) * ASTR + ku * 16 + g * 8];
            f16x8 Ab = *(const f16x8*)&As_l[cur][(mh * 32 + l31) * ASTR + ku * 16 + g * 8];
            acc = __builtin_amdgcn_mfma_f32_32x32x16_f16(Ab, Bh, acc, 0, 0, 0);
            acc = __builtin_amdgcn_mfma_f32_32x32x16_f16(Aa, Bl, acc, 0, 0, 0);
            acc = __builtin_amdgcn_mfma_f32_32x32x16_f16(Aa, Bh, acc, 0, 0, 0);
        }
        __syncthreads();
    }
#undef D2STAGE

    const int colg = ch * 32 + l31;
    #pragma unroll
    for (int r = 0; r < 16; ++r) {
        int m = m0 + mh * 32 + (r & 3) + 8 * (r >> 2) + 4 * g;
        yout[((size_t)b * NN + m) * NC + colg] = lrelu(acc[r]);
    }
}

// ------- Kernel 2 fallback (fused MFMA diffuse, r4) -------
__global__ __launch_bounds__(256) void diffuse_mfma_kernel(
    const float* __restrict__ nv, const float* __restrict__ xin,
    float* __restrict__ yout)
{
    const int b = blockIdx.x;
    const int m0 = blockIdx.y * 128;
    const int t = threadIdx.x;
    const int l = t & 63;
    const int w = t >> 6;
    const int g = l >> 5;
    const int l31 = l & 31;

    __shared__ __align__(16) f16 nvA_h[128 * NVSTR], nvA_l[128 * NVSTR];
    __shared__ __align__(16) f16 nvB_h[2][32 * NVSTR], nvB_l[2][32 * NVSTR];
    __shared__ __align__(16) f16 xT_h[2][64 * XSTR], xT_l[2][64 * XSTR];
    __shared__ __align__(16) f16 S_h[128 * SSTR], S_l[128 * SSTR];

    {
        int row = t >> 1, e0 = (t & 1) * 8;
        const float* src = nv + ((size_t)b * NN + m0 + row) * NE + e0;
        #pragma unroll
        for (int q = 0; q < 4; ++q) {
            float v0 = src[2 * q], v1 = src[2 * q + 1];
            f16 h0 = (f16)v0, h1 = (f16)v1;
            f16 lo0 = (f16)(v0 - (float)h0), lo1 = (f16)(v1 - (float)h1);
            f16x2 ph; ph[0] = h0; ph[1] = h1;
            f16x2 pl; pl[0] = lo0; pl[1] = lo1;
            *(f16x2*)&nvA_h[row * NVSTR + e0 + 2 * q] = ph;
            *(f16x2*)&nvA_l[row * NVSTR + e0 + 2 * q] = pl;
        }
    }

#define STAGE(n0v, bufv) do { \
    if (t < 64) { \
        int nl_ = t >> 1, e0_ = (t & 1) * 8; \
        const float* s_ = nv + ((size_t)b * NN + (n0v) + nl_) * NE + e0_; \
        _Pragma("unroll") \
        for (int q = 0; q < 4; ++q) { \
            float v0 = s_[2 * q], v1 = s_[2 * q + 1]; \
            f16 h0 = (f16)v0, h1 = (f16)v1; \
            f16 lo0 = (f16)(v0 - (float)h0), lo1 = (f16)(v1 - (float)h1); \
            f16x2 ph; ph[0] = h0; ph[1] = h1; \
            f16x2 pl; pl[0] = lo0; pl[1] = lo1; \
            *(f16x2*)&nvB_h[bufv][nl_ * NVSTR + e0_ + 2 * q] = ph; \
            *(f16x2*)&nvB_l[bufv][nl_ * NVSTR + e0_ + 2 * q] = pl; \
        } \
    } \
    { \
        int k_ = t >> 3, c0_ = t & 7; \
        const float* s_ = xin + ((size_t)b * NN + (n0v) + k_) * NC + c0_; \
        _Pragma("unroll") \
        for (int i = 0; i < 8; ++i) { \
            float v = s_[8 * i]; \
            f16 h = (f16)v; f16 lo = (f16)(v - (float)h); \
            int c_ = c0_ + 8 * i; \
            xT_h[bufv][c_ * XSTR + k_] = h; \
            xT_l[bufv][c_ * XSTR + k_] = lo; \
        } \
    } \
} while (0)

    STAGE(0, 0);
    __syncthreads();

    f32x16 acc0, acc1;
    #pragma unroll
    for (int r = 0; r < 16; ++r) { acc0[r] = 0.0f; acc1[r] = 0.0f; }

    const int mh = w & 1;
    const int cc = w >> 1;

    for (int s = 0; s < 32; ++s) {
        const int cur = s & 1;
        {
            f16x8 Ah = *(const f16x8*)&nvA_h[(w * 32 + l31) * NVSTR + g * 8];
            f16x8 Al = *(const f16x8*)&nvA_l[(w * 32 + l31) * NVSTR + g * 8];
            f16x8 Bh = *(const f16x8*)&nvB_h[cur][l31 * NVSTR + g * 8];
            f16x8 Bl = *(const f16x8*)&nvB_l[cur][l31 * NVSTR + g * 8];
            f32x16 sa;
            #pragma unroll
            for (int r = 0; r < 16; ++r) sa[r] = 0.0f;
            sa = __builtin_amdgcn_mfma_f32_32x32x16_f16(Al, Bh, sa, 0, 0, 0);
            sa = __builtin_amdgcn_mfma_f32_32x32x16_f16(Ah, Bl, sa, 0, 0, 0);
            sa = __builtin_amdgcn_mfma_f32_32x32x16_f16(Ah, Bh, sa, 0, 0, 0);
            #pragma unroll
            for (int r = 0; r < 16; ++r) {
                float vv = fmaxf(sa[r], 0.0f);
                f16 h = (f16)vv; f16 lo = (f16)(vv - (float)h);
                int row = w * 32 + (r & 3) + 8 * (r >> 2) + 4 * g;
                S_h[row * SSTR + l31] = h;
                S_l[row * SSTR + l31] = lo;
            }
        }
        if (s + 1 < 32) STAGE((s + 1) * 32, cur ^ 1);
        __syncthreads();
        #pragma unroll
        for (int chh = 0; chh < 2; ++chh) {
            f16x8 Bh = *(const f16x8*)&xT_h[cur][(cc * 32 + l31) * XSTR + chh * 16 + g * 8];
            f16x8 Bl = *(const f16x8*)&xT_l[cur][(cc * 32 + l31) * XSTR + chh * 16 + g * 8];
            {
                int sr = (mh * 64 + l31) * SSTR + chh * 16 + g * 8;
                f16x8 Ah = *(const f16x8*)&S_h[sr];
                f16x8 Al = *(const f16x8*)&S_l[sr];
                acc0 = __builtin_amdgcn_mfma_f32_32x32x16_f16(Al, Bh, acc0, 0, 0, 0);
                acc0 = __builtin_amdgcn_mfma_f32_32x32x16_f16(Ah, Bl, acc0, 0, 0, 0);
                acc0 = __builtin_amdgcn_mfma_f32_32x32x16_f16(Ah, Bh, acc0, 0, 0, 0);
            }
            {
                int sr = (mh * 64 + 32 + l31) * SSTR + chh * 16 + g * 8;
                f16x8 Ah = *(const f16x8*)&S_h[sr];
                f16x8 Al = *(const f16x8*)&S_l[sr];
                acc1 = __builtin_amdgcn_mfma_f32_32x32x16_f16(Al, Bh, acc1, 0, 0, 0);
                acc1 = __builtin_amdgcn_mfma_f32_32x32x16_f16(Ah, Bl, acc1, 0, 0, 0);
                acc1 = __builtin_amdgcn_mfma_f32_32x32x16_f16(Ah, Bh, acc1, 0, 0, 0);
            }
        }
        __syncthreads();
    }
#undef STAGE

    const int colg = cc * 32 + l31;
    #pragma unroll
    for (int r = 0; r < 16; ++r) {
        int row0 = m0 + mh * 64 + (r & 3) + 8 * (r >> 2) + 4 * g;
        yout[((size_t)b * NN + row0) * NC + colg] = lrelu(acc0[r]);
        yout[((size_t)b * NN + row0 + 32) * NC + colg] = lrelu(acc1[r]);
    }
}

// ======= Attention pool, stage A: per-row scores (one wave per row) =======
__global__ __launch_bounds__(256) void scores_kernel(
    const float* __restrict__ x, const float* __restrict__ xs1, const float* __restrict__ xs2,
    const float* __restrict__ xb1, const float* __restrict__ xb2,
    const float* __restrict__ att_w, const float* __restrict__ att_b,
    float* __restrict__ sc)
{
    const int lane = threadIdx.x & 63;
    const int w = threadIdx.x >> 6;
    const int r = blockIdx.x * 4 + w;
    const int which = r >= NB * NN;
    const int rr = r - which * NB * NN;

    const float* p0 = which ? xs2 : x;
    const float* p1 = which ? xb1 : xs1;
    const float* p2 = which ? xb2 : xs2;

    size_t idx = (size_t)rr * NC + lane;
    float nf = (p0[idx] + p1[idx] + p2[idx]) * (1.0f / 3.0f);
    float v = nf * att_w[lane];
    #pragma unroll
    for (int off = 32; off > 0; off >>= 1) v += __shfl_xor(v, off);
    if (lane == 0) sc[r] = v + att_b[0];
}

// ======= Stage B: softmax over the 1024 nodes of one (which,b) =======
__global__ __launch_bounds__(256) void softmax_kernel(float* __restrict__ sc)
{
    const int wb = blockIdx.x;
    const int t = threadIdx.x;
    const int lane = t & 63;
    const int w = t >> 6;
    float* p = sc + (size_t)wb * NN;

    __shared__ float red[4];
    float4 v = reinterpret_cast<const float4*>(p)[t];
    float m = fmaxf(fmaxf(v.x, v.y), fmaxf(v.z, v.w));
    #pragma unroll
    for (int off = 32; off > 0; off >>= 1) m = fmaxf(m, __shfl_xor(m, off));
    if (lane == 0) red[w] = m;
    __syncthreads();
    m = fmaxf(fmaxf(red[0], red[1]), fmaxf(red[2], red[3]));
    __syncthreads();
    v.x = expf(v.x - m); v.y = expf(v.y - m); v.z = expf(v.z - m); v.w = expf(v.w - m);
    float s = v.x + v.y + v.z + v.w;
    #pragma unroll
    for (int off = 32; off > 0; off >>= 1) s += __shfl_xor(s, off);
    if (lane == 0) red[w] = s;
    __syncthreads();
    const float inv = 1.0f / (red[0] + red[1] + red[2] + red[3]);
    v.x *= inv; v.y *= inv; v.z *= inv; v.w *= inv;
    reinterpret_cast<float4*>(p)[t] = v;
}

// ======= Stage C: partial weighted sums over 64-node chunks =======
__global__ __launch_bounds__(256) void poolpart_kernel(
    const float* __restrict__ x, const float* __restrict__ xs1, const float* __restrict__ xs2,
    const float* __restrict__ xb1, const float* __restrict__ xb2,
    const float* __restrict__ sc, float* __restrict__ partial)
{
    const int chunk = blockIdx.x;
    const int b = blockIdx.y;
    const int which = blockIdx.z;
    const int lane = threadIdx.x & 63;
    const int w = threadIdx.x >> 6;

    const float* p0 = which ? xs2 : x;
    const float* p1 = which ? xb1 : xs1;
    const float* p2 = which ? xb2 : xs2;

    const int n0 = chunk * 64;
    const size_t base = (size_t)b * NN;
    float acc = 0.0f;
    for (int j = w; j < 64; j += 4) {
        int n = n0 + j;
        size_t idx = (base + n) * NC + lane;
        float nf = (p0[idx] + p1[idx] + p2[idx]) * (1.0f / 3.0f);
        acc += nf * sc[((size_t)which * NB + b) * NN + n];
    }
    __shared__ float red[4][64];
    red[w][lane] = acc;
    __syncthreads();
    if (w == 0) {
        float s = red[0][lane] + red[1][lane] + red[2][lane] + red[3][lane];
        partial[(((size_t)which * NB + b) * 16 + chunk) * 64 + lane] = s;
    }
}

// ======= Stage D: reduce partials + multiply by weights1 =======
__global__ __launch_bounds__(256) void poolfin_kernel(
    const float* __restrict__ partial, const float* __restrict__ w1,
    float* __restrict__ gf_out)
{
    const int wb = blockIdx.x;
    const int t = threadIdx.x;
    const int lane = t & 63;
    const int w = t >> 6;

    __shared__ float red[4][64];
    __shared__ float gfin[64];
    float acc = 0.0f;
    #pragma unroll
    for (int r = w; r < 16; r += 4)
        acc += partial[((size_t)wb * 16 + r) * 64 + lane];
    red[w][lane] = acc;
    __syncthreads();
    if (w == 0) gfin[lane] = red[0][lane] + red[1][lane] + red[2][lane] + red[3][lane];
    __syncthreads();
    if (w == 0) {
        float s = 0.0f;
        #pragma unroll
        for (int c = 0; c < 64; ++c) s += gfin[c] * w1[c * 64 + lane];
        gf_out[(size_t)wb * 64 + lane] = s;
    }
}

// ------- Kernel 4a: W[n][ki][o] = sum_e emb1[n,e] * pool[e][ki][o] (grid 192 x 4) -------
__global__ __launch_bounds__(256) void wbuild_kernel(
    const float* __restrict__ emb1, const float* __restrict__ pool,
    float* __restrict__ W)
{
    const int ki = blockIdx.x;            // 0..191
    const int chunk = blockIdx.y;         // 0..3
    const int t = threadIdx.x;
    const int o = t & 63;

    __shared__ float slab[16][64];
    __shared__ float eloc[256][16];

    for (int idx = t; idx < 1024; idx += 256)
        slab[idx >> 6][idx & 63] = pool[((size_t)(idx >> 6) * 192 + ki) * 64 + (idx & 63)];
    for (int idx = t; idx < 4096; idx += 256)
        eloc[idx >> 4][idx & 15] = emb1[((size_t)chunk * 256 + (idx >> 4)) * 16 + (idx & 15)];
    __syncthreads();
    for (int nl = t >> 6; nl < 256; nl += 4) {
        float s = 0.0f;
        #pragma unroll
        for (int e = 0; e < 16; ++e) s += eloc[nl][e] * slab[e][o];
        W[((size_t)(chunk * 256 + nl) * 192 + ki) * 64 + o] = s;
    }
}

// ------- Kernel 4b: per node n, out[b,o] (pass0: = a*d + bias + gf; pass1: += b*d) -------
__global__ __launch_bounds__(256) void apply_kernel(
    const float* __restrict__ W, const float* __restrict__ emb1,
    const float* __restrict__ bias_pool,
    const float* __restrict__ s0, const float* __restrict__ s1, const float* __restrict__ s2,
    const float* __restrict__ gf, const float* __restrict__ scale,
    float* __restrict__ out, int pass)
{
    const int n = blockIdx.x;
    const int t = threadIdx.x;
    const int o = t & 63;
    const int bg = t >> 6;

    __shared__ float Wn[192][64];
    __shared__ float Xs[3][32][64];
    __shared__ float e1s[16];

    if (t < 16) e1s[t] = emb1[n * 16 + t];
    {
        const float4* src = reinterpret_cast<const float4*>(W + (size_t)n * 192 * 64);
        float4* dst = reinterpret_cast<float4*>(&Wn[0][0]);
        #pragma unroll
        for (int r = 0; r < 12; ++r) dst[t + 256 * r] = src[t + 256 * r];
    }
    const float* srcs[3] = {s0, s1, s2};
    #pragma unroll
    for (int k = 0; k < 3; ++k) {
        const float* sp = srcs[k];
        #pragma unroll
        for (int r = 0; r < 2; ++r) {
            int idx = t + 256 * r;
            int b = idx >> 4, i4 = idx & 15;
            reinterpret_cast<float4*>(&Xs[k][b][0])[i4] =
                reinterpret_cast<const float4*>(sp + ((size_t)b * NN + n) * NC)[i4];
        }
    }
    __syncthreads();

    float acc[8] = {};
    #pragma unroll 4
    for (int ki = 0; ki < 192; ++ki) {
        float wv = Wn[ki][o];
        int k = ki >> 6, i = ki & 63;
        #pragma unroll
        for (int j = 0; j < 8; ++j) acc[j] += Xs[k][bg * 8 + j][i] * wv;
    }

    const float sc = scale[0];
    if (pass == 0) {
        float bias_o = 0.0f;
        #pragma unroll
        for (int e = 0; e < 16; ++e) bias_o += e1s[e] * bias_pool[e * 64 + o];
        #pragma unroll
        for (int j = 0; j < 8; ++j) {
            int b = bg * 8 + j;
            float g = gf[(size_t)b * 64 + o] + gf[((size_t)NB + b) * 64 + o];
            out[((size_t)b * NN + n) * NC + o] = sc * acc[j] + bias_o + g;
        }
    } else {
        #pragma unroll
        for (int j = 0; j < 8; ++j) {
            int b = bg * 8 + j;
            out[((size_t)b * NN + n) * NC + o] += sc * acc[j];
        }
    }
}

// ------- Fallback final kernel (ws too small) -------
__global__ __launch_bounds__(256) void final_kernel(
    const float* __restrict__ emb1,
    const float* __restrict__ wpf, const float* __restrict__ wpb,
    const float* __restrict__ bias_pool,
    const float* __restrict__ x, const float* __restrict__ xs1, const float* __restrict__ xs2,
    const float* __restrict__ xb1, const float* __restrict__ xb2,
    const float* __restrict__ gf, const float* __restrict__ alpha, const float* __restrict__ beta,
    float* __restrict__ out)
{
    const int n = blockIdx.x;
    const int t = threadIdx.x;
    const int o = t & 63;
    const int bg = t >> 6;

    __shared__ float Wk[64][64];
    __shared__ float xk[32][64];
    __shared__ float e1[16];
    if (t < 16) e1[t] = emb1[n * 16 + t];

    float acc[2][8];
    #pragma unroll
    for (int d = 0; d < 2; ++d)
        #pragma unroll
        for (int j = 0; j < 8; ++j) acc[d][j] = 0.0f;

    const float* srcs[2][3] = {{x, xs1, xs2}, {xs2, xb1, xb2}};

    #pragma unroll
    for (int dir = 0; dir < 2; ++dir) {
        const float* wp = dir ? wpb : wpf;
        #pragma unroll
        for (int k = 0; k < 3; ++k) {
            __syncthreads();
            for (int idx = t; idx < 4096; idx += 256) {
                int i = idx >> 6, oo = idx & 63;
                float s = 0.0f;
                #pragma unroll
                for (int e = 0; e < 16; ++e) s += e1[e] * wp[(((size_t)e * 3 + k) * 64 + i) * 64 + oo];
                Wk[i][oo] = s;
            }
            const float* src = srcs[dir][k];
            for (int idx = t; idx < 2048; idx += 256) {
                int bb = idx >> 6, ii = idx & 63;
                xk[bb][ii] = src[((size_t)bb * NN + n) * NC + ii];
            }
            __syncthreads();
            #pragma unroll
            for (int j = 0; j < 8; ++j) {
                int bb = bg * 8 + j;
                float s = 0.0f;
                #pragma unroll
                for (int i = 0; i < 64; i += 4) {
                    float4 xv = *reinterpret_cast<const float4*>(&xk[bb][i]);
                    s += xv.x * Wk[i][o] + xv.y * Wk[i + 1][o] + xv.z * Wk[i + 2][o] + xv.w * Wk[i + 3][o];
                }
                acc[dir][j] += s;
            }
        }
    }

    float bias_o = 0.0f;
    #pragma unroll
    for (int e = 0; e < 16; ++e) bias_o += e1[e] * bias_pool[e * 64 + o];
    const float al = alpha[0], be = beta[0];
    #pragma unroll
    for (int j = 0; j < 8; ++j) {
        int bb = bg * 8 + j;
        float g = gf[(size_t)bb * 64 + o] + gf[((size_t)NB + bb) * 64 + o];
        out[((size_t)bb * NN + n) * NC + o] = al * acc[0][j] + be * acc[1][j] + bias_o + g;
    }
}

// ------- Fallback attnpool (ws too small) -------
__global__ __launch_bounds__(256) void attnpool_kernel(
    const float* __restrict__ a0, const float* __restrict__ a1, const float* __restrict__ a2,
    const float* __restrict__ c0, const float* __restrict__ c1, const float* __restrict__ c2,
    const float* __restrict__ att_w, const float* __restrict__ att_b,
    const float* __restrict__ w1, float* __restrict__ gf_out)
{
    const int b = blockIdx.x;
    const int which = blockIdx.y;
    const float* p0 = which ? c0 : a0;
    const float* p1 = which ? c1 : a1;
    const float* p2 = which ? c2 : a2;
    const int t = threadIdx.x;
    const int lane = t & 63;
    const int w = t >> 6;

    __shared__ float sc[NN];
    __shared__ float red[4];
    __shared__ float gfp[4][64];
    __shared__ float gfin[64];

    const float aw = att_w[lane];
    const size_t base = (size_t)b * NN * NC;

    for (int n = w; n < NN; n += 4) {
        size_t idx = base + (size_t)n * NC + lane;
        float nf = (p0[idx] + p1[idx] + p2[idx]) * (1.0f / 3.0f);
        float v = nf * aw;
        #pragma unroll
        for (int off = 32; off > 0; off >>= 1) v += __shfl_xor(v, off);
        if (lane == 0) sc[n] = v + att_b[0];
    }
    __syncthreads();
    float m = -INFINITY;
    for (int i = t; i < NN; i += 256) m = fmaxf(m, sc[i]);
    #pragma unroll
    for (int off = 32; off > 0; off >>= 1) m = fmaxf(m, __shfl_xor(m, off));
    if (lane == 0) red[w] = m;
    __syncthreads();
    m = fmaxf(fmaxf(red[0], red[1]), fmaxf(red[2], red[3]));
    __syncthreads();
    float s = 0.0f;
    for (int i = t; i < NN; i += 256) { float e = expf(sc[i] - m); sc[i] = e; s += e; }
    #pragma unroll
    for (int off = 32; off > 0; off >>= 1) s += __shfl_xor(s, off);
    if (lane == 0) red[w] = s;
    __syncthreads();
    const float inv_denom = 1.0f / (red[0] + red[1] + red[2] + red[3]);

    float acc = 0.0f;
    for (int n = w; n < NN; n += 4) {
        size_t idx = base + (size_t)n * NC + lane;
        float nf = (p0[idx] + p1[idx] + p2[idx]) * (1.0f / 3.0f);
        acc += nf * sc[n];
    }
    gfp[w][lane] = acc;
    __syncthreads();
    if (w == 0) gfin[lane] = (gfp[0][lane] + gfp[1][lane] + gfp[2][lane] + gfp[3][lane]) * inv_denom;
    __syncthreads();
    if (w == 0) {
        float s2 = 0.0f;
        #pragma unroll
        for (int c = 0; c < 64; ++c) s2 += gfin[c] * w1[c * 64 + lane];
        gf_out[((size_t)which * NB + b) * 64 + lane] = s2;
    }
}

extern "C" void kernel_launch(void* const* d_in, const int* in_sizes, int n_in,
                              void* d_out, int out_size, void* d_ws, size_t ws_size,
                              hipStream_t stream)
{
    const float* x      = (const float*)d_in[0];
    const float* emb0   = (const float*)d_in[1];
    const float* emb1   = (const float*)d_in[2];
    const float* speed  = (const float*)d_in[5];
    const float* occupy = (const float*)d_in[6];
    const float* fw1 = (const float*)d_in[7];
    const float* fb1 = (const float*)d_in[8];
    const float* fw2 = (const float*)d_in[9];
    const float* fb2 = (const float*)d_in[10];
    const float* fw3 = (const float*)d_in[11];
    const float* fb3 = (const float*)d_in[12];
    const float* gw1 = (const float*)d_in[13];
    const float* gb1 = (const float*)d_in[14];
    const float* gw2 = (const float*)d_in[15];
    const float* gb2 = (const float*)d_in[16];
    const float* gw3 = (const float*)d_in[17];
    const float* gb3 = (const float*)d_in[18];
    const float* alpha = (const float*)d_in[19];
    const float* beta  = (const float*)d_in[20];
    const float* wpf = (const float*)d_in[21];
    const float* wpb = (const float*)d_in[22];
    const float* bias_pool = (const float*)d_in[23];
    const float* w1 = (const float*)d_in[24];
    const float* att_w = (const float*)d_in[25];
    const float* att_b = (const float*)d_in[26];
    float* out = (float*)d_out;

    float* ws = (float*)d_ws;
    float* nv  = ws;                                   // B*N*E
    float* xs1 = nv + (size_t)NB * NN * NE;            // B*N*C each
    float* xs2 = xs1 + (size_t)NB * NN * NC;
    float* xb1 = xs2 + (size_t)NB * NN * NC;
    float* xb2 = xb1 + (size_t)NB * NN * NC;
    float* gfb = xb2 + (size_t)NB * NN * NC;           // [2][B][64]
    float* scb = gfb + 4096;                           // [2][B][N]
    float* ppb = scb + (size_t)2 * NB * NN;            // [2][B][16][64]
    float* Wbuf = ppb + (size_t)2 * NB * 16 * 64;      // N*192*64
    f16* Sh = (f16*)(Wbuf + (size_t)NN * 192 * 64);    // B*N*N f16 planes
    f16* Sl = Sh + (size_t)NB * NN * NN;

    const size_t base_elems = (size_t)NB * NN * NE + 4 * (size_t)NB * NN * NC + 4096;
    const size_t attn_elems = (size_t)2 * NB * NN + (size_t)2 * NB * 16 * 64;
    const size_t w_elems = (size_t)NN * 192 * 64;
    const size_t need_mid = (base_elems + attn_elems + w_elems) * sizeof(float);
    const size_t need_full = need_mid + (size_t)2 * NB * NN * NN * sizeof(f16);

    hipLaunchKernelGGL(nv_kernel, dim3(NB * NN / 4), dim3(256), 0, stream,
                       x, emb0, speed, occupy, fw1, fb1, fw2, fb2, fw3, fb3,
                       gw1, gb1, gw2, gb2, gw3, gb3, nv);

    if (ws_size >= need_full) {
        hipLaunchKernelGGL(sgen_kernel, dim3(NB, NN / 128), dim3(256), 0, stream, nv, Sh, Sl);
        dim3 gd2(NB, NN / 64);
        hipLaunchKernelGGL(diffuse2_kernel, gd2, dim3(256), 0, stream, Sh, Sl, x, xs1);
        hipLaunchKernelGGL(diffuse2_kernel, gd2, dim3(256), 0, stream, Sh, Sl, xs1, xs2);
        hipLaunchKernelGGL(diffuse2_kernel, gd2, dim3(256), 0, stream, Sh, Sl, xs2, xb1);
        hipLaunchKernelGGL(diffuse2_kernel, gd2, dim3(256), 0, stream, Sh, Sl, xb1, xb2);
    } else {
        dim3 gd(NB, NN / 128);
        hipLaunchKernelGGL(diffuse_mfma_kernel, gd, dim3(256), 0, stream, nv, x, xs1);
        hipLaunchKernelGGL(diffuse_mfma_kernel, gd, dim3(256), 0, stream, nv, xs1, xs2);
        hipLaunchKernelGGL(diffuse_mfma_kernel, gd, dim3(256), 0, stream, nv, xs2, xb1);
        hipLaunchKernelGGL(diffuse_mfma_kernel, gd, dim3(256), 0, stream, nv, xb1, xb2);
    }

    if (ws_size >= need_mid) {
        hipLaunchKernelGGL(scores_kernel, dim3(2 * NB * NN / 4), dim3(256), 0, stream,
                           x, xs1, xs2, xb1, xb2, att_w, att_b, scb);
        hipLaunchKernelGGL(softmax_kernel, dim3(2 * NB), dim3(256), 0, stream, scb);
        hipLaunchKernelGGL(poolpart_kernel, dim3(16, NB, 2), dim3(256), 0, stream,
                           x, xs1, xs2, xb1, xb2, scb, ppb);
        hipLaunchKernelGGL(poolfin_kernel, dim3(2 * NB), dim3(256), 0, stream, ppb, w1, gfb);
        hipLaunchKernelGGL(wbuild_kernel, dim3(192, 4), dim3(256), 0, stream, emb1, wpf, Wbuf);
        hipLaunchKernelGGL(apply_kernel, dim3(NN), dim3(256), 0, stream,
                           Wbuf, emb1, bias_pool, x, xs1, xs2, gfb, alpha, out, 0);
        hipLaunchKernelGGL(wbuild_kernel, dim3(192, 4), dim3(256), 0, stream, emb1, wpb, Wbuf);
        hipLaunchKernelGGL(apply_kernel, dim3(NN), dim3(256), 0, stream,
                           Wbuf, emb1, bias_pool, xs2, xb1, xb2, gfb, beta, out, 1);
    } else {
        hipLaunchKernelGGL(attnpool_kernel, dim3(NB, 2), dim3(256), 0, stream,
                           x, xs1, xs2, xs2, xb1, xb2, att_w, att_b, w1, gfb);
        hipLaunchKernelGGL(final_kernel, dim3(NN), dim3(256), 0, stream,
                           emb1, wpf, wpb, bias_pool, x, xs1, xs2, xb1, xb2, gfb, alpha, beta, out);
    }
}

// Round 6
// 313.096 us; speedup vs baseline: 10.0670x; 1.0502x over previous
//
#include <hip/hip_runtime.h>
#include <cmath>

#define NB 32
#define NN 1024
#define NC 64
#define NE 16

typedef _Float16 f16;
typedef __attribute__((ext_vector_type(2))) _Float16 f16x2;
typedef __attribute__((ext_vector_type(8))) _Float16 f16x8;
typedef __attribute__((ext_vector_type(16))) float f32x16;

#define NVSTR 24   // f16 per row: 16 data + 8 pad
#define SSTR  40
#define XSTR  40
#define ASTR  40

__device__ __forceinline__ float sigm(float v) { return 1.0f / (1.0f + expf(-v)); }
__device__ __forceinline__ float lrelu(float v) { return v > 0.0f ? v : 0.01f * v; }

// ---------------- Kernel 1: nv = tanh(tanh(tanh(emb0*filt)*f1)*f2) ----------------
// One thread per row (b*N+n). No LDS, no barriers: weights are lane-uniform
// (scalar loads), x-row streamed per lane (wave working set 16 KB -> L1).
__global__ __launch_bounds__(64) void nv_kernel(
    const float* __restrict__ x, const float* __restrict__ emb0,
    const float* __restrict__ speed, const float* __restrict__ occupy,
    const float* __restrict__ fw1, const float* __restrict__ fb1,
    const float* __restrict__ fw2, const float* __restrict__ fb2,
    const float* __restrict__ fw3, const float* __restrict__ fb3,
    const float* __restrict__ gw1, const float* __restrict__ gb1,
    const float* __restrict__ gw2, const float* __restrict__ gb2,
    const float* __restrict__ gw3, const float* __restrict__ gb3,
    float* __restrict__ nv_out)
{
    const int row = blockIdx.x * 64 + threadIdx.x;   // 0 .. B*N-1

    // ---- fc: h1 = sigm(x @ fw1^T + fb1) ----
    float h1[16];
    #pragma unroll
    for (int j = 0; j < 16; ++j) h1[j] = fb1[j];
    {
        const float4* xr = reinterpret_cast<const float4*>(x + (size_t)row * 64);
        #pragma unroll
        for (int i4 = 0; i4 < 16; ++i4) {
            float4 xv = xr[i4];
            #pragma unroll
            for (int j = 0; j < 16; ++j) {
                const float* wr = fw1 + j * 64 + i4 * 4;
                h1[j] += xv.x * wr[0] + xv.y * wr[1] + xv.z * wr[2] + xv.w * wr[3];
            }
        }
    }
    #pragma unroll
    for (int j = 0; j < 16; ++j) h1[j] = sigm(h1[j]);

    // ---- fc: h2 = sigm(h1 @ fw2^T + fb2) ----
    float h2a = fb2[0], h2b = fb2[1];
    #pragma unroll
    for (int j = 0; j < 16; ++j) { h2a += h1[j] * fw2[j]; h2b += h1[j] * fw2[16 + j]; }
    h2a = sigm(h2a); h2b = sigm(h2b);

    // ---- fc1 paths for speed and occupy (shared weights gw*) ----
    const float sp = speed[row], oc = occupy[row];
    float ga = gb2[0], gb_ = gb2[1];
    float oa = gb2[0], ob_ = gb2[1];
    #pragma unroll
    for (int j = 0; j < 16; ++j) {
        float g1 = sigm(sp * gw1[j] + gb1[j]);
        float o1 = sigm(oc * gw1[j] + gb1[j]);
        ga += g1 * gw2[j];  gb_ += g1 * gw2[16 + j];
        oa += o1 * gw2[j];  ob_ += o1 * gw2[16 + j];
    }
    ga = sigm(ga); gb_ = sigm(gb_); oa = sigm(oa); ob_ = sigm(ob_);

    // ---- nv = tanh(tanh(tanh(emb0*filt)*f1)*f2) ----
    const float* e0 = emb0 + (size_t)row * 16;
    float vout[16];
    #pragma unroll
    for (int j = 0; j < 16; ++j) {
        float filt = h2a * fw3[j * 2] + h2b * fw3[j * 2 + 1] + fb3[j];
        float f1v  = ga  * gw3[j * 2] + gb_ * gw3[j * 2 + 1] + gb3[j];
        float f2v  = oa  * gw3[j * 2] + ob_ * gw3[j * 2 + 1] + gb3[j];
        float v = tanhf(e0[j] * filt);
        v = tanhf(v * f1v);
        v = tanhf(v * f2v);
        vout[j] = v;
    }
    float4* dst = reinterpret_cast<float4*>(nv_out + (size_t)row * 16);
    #pragma unroll
    for (int q = 0; q < 4; ++q) {
        float4 o; o.x = vout[4 * q]; o.y = vout[4 * q + 1]; o.z = vout[4 * q + 2]; o.w = vout[4 * q + 3];
        dst[q] = o;
    }
}

// ------- sgen: materialize S = relu(nv nv^T) as split f16 planes Sh/Sl [b][m][n] -------
__global__ __launch_bounds__(256) void sgen_kernel(
    const float* __restrict__ nv, f16* __restrict__ Sh, f16* __restrict__ Sl)
{
    const int b = blockIdx.x;
    const int m0 = blockIdx.y * 128;
    const int t = threadIdx.x;
    const int l = t & 63;
    const int w = t >> 6;
    const int g = l >> 5;
    const int l31 = l & 31;

    __shared__ __align__(16) f16 nvA_h[128 * NVSTR], nvA_l[128 * NVSTR];
    __shared__ __align__(16) f16 nvB_h[128 * NVSTR], nvB_l[128 * NVSTR];

    {
        int row = t >> 1, e0 = (t & 1) * 8;
        const float* src = nv + ((size_t)b * NN + m0 + row) * NE + e0;
        #pragma unroll
        for (int q = 0; q < 4; ++q) {
            float v0 = src[2 * q], v1 = src[2 * q + 1];
            f16 h0 = (f16)v0, h1 = (f16)v1;
            f16 lo0 = (f16)(v0 - (float)h0), lo1 = (f16)(v1 - (float)h1);
            f16x2 ph; ph[0] = h0; ph[1] = h1;
            f16x2 pl; pl[0] = lo0; pl[1] = lo1;
            *(f16x2*)&nvA_h[row * NVSTR + e0 + 2 * q] = ph;
            *(f16x2*)&nvA_l[row * NVSTR + e0 + 2 * q] = pl;
        }
    }
    const size_t sbase = (size_t)b * NN * NN;
    for (int it = 0; it < 8; ++it) {
        __syncthreads();   // nvB free (prev compute done)
        {
            int row = t >> 1, e0 = (t & 1) * 8;
            const float* src = nv + ((size_t)b * NN + it * 128 + row) * NE + e0;
            #pragma unroll
            for (int q = 0; q < 4; ++q) {
                float v0 = src[2 * q], v1 = src[2 * q + 1];
                f16 h0 = (f16)v0, h1 = (f16)v1;
                f16 lo0 = (f16)(v0 - (float)h0), lo1 = (f16)(v1 - (float)h1);
                f16x2 ph; ph[0] = h0; ph[1] = h1;
                f16x2 pl; pl[0] = lo0; pl[1] = lo1;
                *(f16x2*)&nvB_h[row * NVSTR + e0 + 2 * q] = ph;
                *(f16x2*)&nvB_l[row * NVSTR + e0 + 2 * q] = pl;
            }
        }
        __syncthreads();
        f16x8 Ah = *(const f16x8*)&nvA_h[(w * 32 + l31) * NVSTR + g * 8];
        f16x8 Al = *(const f16x8*)&nvA_l[(w * 32 + l31) * NVSTR + g * 8];
        #pragma unroll
        for (int tile = 0; tile < 4; ++tile) {
            f16x8 Bh = *(const f16x8*)&nvB_h[(tile * 32 + l31) * NVSTR + g * 8];
            f16x8 Bl = *(const f16x8*)&nvB_l[(tile * 32 + l31) * NVSTR + g * 8];
            f32x16 sa;
            #pragma unroll
            for (int r = 0; r < 16; ++r) sa[r] = 0.0f;
            sa = __builtin_amdgcn_mfma_f32_32x32x16_f16(Al, Bh, sa, 0, 0, 0);
            sa = __builtin_amdgcn_mfma_f32_32x32x16_f16(Ah, Bl, sa, 0, 0, 0);
            sa = __builtin_amdgcn_mfma_f32_32x32x16_f16(Ah, Bh, sa, 0, 0, 0);
            const int n = it * 128 + tile * 32 + l31;
            #pragma unroll
            for (int r = 0; r < 16; ++r) {
                float vv = fmaxf(sa[r], 0.0f);
                f16 h = (f16)vv; f16 lo = (f16)(vv - (float)h);
                int m = m0 + w * 32 + (r & 3) + 8 * (r >> 2) + 4 * g;
                Sh[sbase + (size_t)m * NN + n] = h;
                Sl[sbase + (size_t)m * NN + n] = lo;
            }
        }
    }
}

// ------- diffuse2: y = lrelu(S x) reading materialized split S; M-tile 64, dbuf LDS -------
__global__ __launch_bounds__(256) void diffuse2_kernel(
    const f16* __restrict__ Sh, const f16* __restrict__ Sl,
    const float* __restrict__ xin, float* __restrict__ yout)
{
    const int b = blockIdx.x;
    const int m0 = blockIdx.y * 64;
    const int t = threadIdx.x;
    const int l = t & 63;
    const int g = l >> 5;
    const int l31 = l & 31;
    const int w = t >> 6;
    const int mh = w & 1;
    const int ch = w >> 1;

    __shared__ __align__(16) f16 As_h[2][64 * ASTR], As_l[2][64 * ASTR];
    __shared__ __align__(16) f16 Xs_h[2][64 * XSTR], Xs_l[2][64 * XSTR];

    const size_t sbase = (size_t)b * NN * NN + (size_t)m0 * NN;
    const int arow = t >> 2, akc = t & 3;
    const int xk = t >> 3, xc0 = t & 7;

#define D2STAGE(n0v, bufv) do { \
    *(f16x8*)&As_h[bufv][arow * ASTR + akc * 8] = \
        *(const f16x8*)&Sh[sbase + (size_t)arow * NN + (n0v) + akc * 8]; \
    *(f16x8*)&As_l[bufv][arow * ASTR + akc * 8] = \
        *(const f16x8*)&Sl[sbase + (size_t)arow * NN + (n0v) + akc * 8]; \
    { \
        const float* xs_ = xin + ((size_t)b * NN + (n0v) + xk) * NC + xc0; \
        _Pragma("unroll") \
        for (int i = 0; i < 8; ++i) { \
            float v = xs_[8 * i]; \
            f16 h = (f16)v; f16 lo = (f16)(v - (float)h); \
            int c_ = xc0 + 8 * i; \
            Xs_h[bufv][c_ * XSTR + xk] = h; \
            Xs_l[bufv][c_ * XSTR + xk] = lo; \
        } \
    } \
} while (0)

    D2STAGE(0, 0);
    f32x16 acc;
    #pragma unroll
    for (int r = 0; r < 16; ++r) acc[r] = 0.0f;
    __syncthreads();

    for (int s = 0; s < 32; ++s) {
        const int cur = s & 1;
        if (s + 1 < 32) D2STAGE((s + 1) * 32, cur ^ 1);
        #pragma unroll
        for (int ku = 0; ku < 2; ++ku) {
            f16x8 Bh = *(const f16x8*)&Xs_h[cur][(ch * 32 + l31) * XSTR + ku * 16 + g * 8];
            f16x8 Bl = *(const f16x8*)&Xs_l[cur][(ch * 32 + l31) * XSTR + ku * 16 + g * 8];
            f16x8 Aa = *(const f16x8*)&As_h[cur][(mh * 32 + l31) * ASTR + ku * 16 + g * 8];
            f16x8 Ab = *(const f16x8*)&As_l[cur][(mh * 32 + l31) * ASTR + ku * 16 + g * 8];
            acc = __builtin_amdgcn_mfma_f32_32x32x16_f16(Ab, Bh, acc, 0, 0, 0);
            acc = __builtin_amdgcn_mfma_f32_32x32x16_f16(Aa, Bl, acc, 0, 0, 0);
            acc = __builtin_amdgcn_mfma_f32_32x32x16_f16(Aa, Bh, acc, 0, 0, 0);
        }
        __syncthreads();
    }
#undef D2STAGE

    const int colg = ch * 32 + l31;
    #pragma unroll
    for (int r = 0; r < 16; ++r) {
        int m = m0 + mh * 32 + (r & 3) + 8 * (r >> 2) + 4 * g;
        yout[((size_t)b * NN + m) * NC + colg] = lrelu(acc[r]);
    }
}

// ------- Fallback (fused MFMA diffuse, r4) -------
__global__ __launch_bounds__(256) void diffuse_mfma_kernel(
    const float* __restrict__ nv, const float* __restrict__ xin,
    float* __restrict__ yout)
{
    const int b = blockIdx.x;
    const int m0 = blockIdx.y * 128;
    const int t = threadIdx.x;
    const int l = t & 63;
    const int w = t >> 6;
    const int g = l >> 5;
    const int l31 = l & 31;

    __shared__ __align__(16) f16 nvA_h[128 * NVSTR], nvA_l[128 * NVSTR];
    __shared__ __align__(16) f16 nvB_h[2][32 * NVSTR], nvB_l[2][32 * NVSTR];
    __shared__ __align__(16) f16 xT_h[2][64 * XSTR], xT_l[2][64 * XSTR];
    __shared__ __align__(16) f16 S_h[128 * SSTR], S_l[128 * SSTR];

    {
        int row = t >> 1, e0 = (t & 1) * 8;
        const float* src = nv + ((size_t)b * NN + m0 + row) * NE + e0;
        #pragma unroll
        for (int q = 0; q < 4; ++q) {
            float v0 = src[2 * q], v1 = src[2 * q + 1];
            f16 h0 = (f16)v0, h1 = (f16)v1;
            f16 lo0 = (f16)(v0 - (float)h0), lo1 = (f16)(v1 - (float)h1);
            f16x2 ph; ph[0] = h0; ph[1] = h1;
            f16x2 pl; pl[0] = lo0; pl[1] = lo1;
            *(f16x2*)&nvA_h[row * NVSTR + e0 + 2 * q] = ph;
            *(f16x2*)&nvA_l[row * NVSTR + e0 + 2 * q] = pl;
        }
    }

#define STAGE(n0v, bufv) do { \
    if (t < 64) { \
        int nl_ = t >> 1, e0_ = (t & 1) * 8; \
        const float* s_ = nv + ((size_t)b * NN + (n0v) + nl_) * NE + e0_; \
        _Pragma("unroll") \
        for (int q = 0; q < 4; ++q) { \
            float v0 = s_[2 * q], v1 = s_[2 * q + 1]; \
            f16 h0 = (f16)v0, h1 = (f16)v1; \
            f16 lo0 = (f16)(v0 - (float)h0), lo1 = (f16)(v1 - (float)h1); \
            f16x2 ph; ph[0] = h0; ph[1] = h1; \
            f16x2 pl; pl[0] = lo0; pl[1] = lo1; \
            *(f16x2*)&nvB_h[bufv][nl_ * NVSTR + e0_ + 2 * q] = ph; \
            *(f16x2*)&nvB_l[bufv][nl_ * NVSTR + e0_ + 2 * q] = pl; \
        } \
    } \
    { \
        int k_ = t >> 3, c0_ = t & 7; \
        const float* s_ = xin + ((size_t)b * NN + (n0v) + k_) * NC + c0_; \
        _Pragma("unroll") \
        for (int i = 0; i < 8; ++i) { \
            float v = s_[8 * i]; \
            f16 h = (f16)v; f16 lo = (f16)(v - (float)h); \
            int c_ = c0_ + 8 * i; \
            xT_h[bufv][c_ * XSTR + k_] = h; \
            xT_l[bufv][c_ * XSTR + k_] = lo; \
        } \
    } \
} while (0)

    STAGE(0, 0);
    __syncthreads();

    f32x16 acc0, acc1;
    #pragma unroll
    for (int r = 0; r < 16; ++r) { acc0[r] = 0.0f; acc1[r] = 0.0f; }

    const int mh = w & 1;
    const int cc = w >> 1;

    for (int s = 0; s < 32; ++s) {
        const int cur = s & 1;
        {
            f16x8 Ah = *(const f16x8*)&nvA_h[(w * 32 + l31) * NVSTR + g * 8];
            f16x8 Al = *(const f16x8*)&nvA_l[(w * 32 + l31) * NVSTR + g * 8];
            f16x8 Bh = *(const f16x8*)&nvB_h[cur][l31 * NVSTR + g * 8];
            f16x8 Bl = *(const f16x8*)&nvB_l[cur][l31 * NVSTR + g * 8];
            f32x16 sa;
            #pragma unroll
            for (int r = 0; r < 16; ++r) sa[r] = 0.0f;
            sa = __builtin_amdgcn_mfma_f32_32x32x16_f16(Al, Bh, sa, 0, 0, 0);
            sa = __builtin_amdgcn_mfma_f32_32x32x16_f16(Ah, Bl, sa, 0, 0, 0);
            sa = __builtin_amdgcn_mfma_f32_32x32x16_f16(Ah, Bh, sa, 0, 0, 0);
            #pragma unroll
            for (int r = 0; r < 16; ++r) {
                float vv = fmaxf(sa[r], 0.0f);
                f16 h = (f16)vv; f16 lo = (f16)(vv - (float)h);
                int row = w * 32 + (r & 3) + 8 * (r >> 2) + 4 * g;
                S_h[row * SSTR + l31] = h;
                S_l[row * SSTR + l31] = lo;
            }
        }
        if (s + 1 < 32) STAGE((s + 1) * 32, cur ^ 1);
        __syncthreads();
        #pragma unroll
        for (int chh = 0; chh < 2; ++chh) {
            f16x8 Bh = *(const f16x8*)&xT_h[cur][(cc * 32 + l31) * XSTR + chh * 16 + g * 8];
            f16x8 Bl = *(const f16x8*)&xT_l[cur][(cc * 32 + l31) * XSTR + chh * 16 + g * 8];
            {
                int sr = (mh * 64 + l31) * SSTR + chh * 16 + g * 8;
                f16x8 Ah = *(const f16x8*)&S_h[sr];
                f16x8 Al = *(const f16x8*)&S_l[sr];
                acc0 = __builtin_amdgcn_mfma_f32_32x32x16_f16(Al, Bh, acc0, 0, 0, 0);
                acc0 = __builtin_amdgcn_mfma_f32_32x32x16_f16(Ah, Bl, acc0, 0, 0, 0);
                acc0 = __builtin_amdgcn_mfma_f32_32x32x16_f16(Ah, Bh, acc0, 0, 0, 0);
            }
            {
                int sr = (mh * 64 + 32 + l31) * SSTR + chh * 16 + g * 8;
                f16x8 Ah = *(const f16x8*)&S_h[sr];
                f16x8 Al = *(const f16x8*)&S_l[sr];
                acc1 = __builtin_amdgcn_mfma_f32_32x32x16_f16(Al, Bh, acc1, 0, 0, 0);
                acc1 = __builtin_amdgcn_mfma_f32_32x32x16_f16(Ah, Bl, acc1, 0, 0, 0);
                acc1 = __builtin_amdgcn_mfma_f32_32x32x16_f16(Ah, Bh, acc1, 0, 0, 0);
            }
        }
        __syncthreads();
    }
#undef STAGE

    const int colg = cc * 32 + l31;
    #pragma unroll
    for (int r = 0; r < 16; ++r) {
        int row0 = m0 + mh * 64 + (r & 3) + 8 * (r >> 2) + 4 * g;
        yout[((size_t)b * NN + row0) * NC + colg] = lrelu(acc0[r]);
        yout[((size_t)b * NN + row0 + 32) * NC + colg] = lrelu(acc1[r]);
    }
}

// ======= Attention pool, stage A: per-row scores (one wave per row) =======
__global__ __launch_bounds__(256) void scores_kernel(
    const float* __restrict__ x, const float* __restrict__ xs1, const float* __restrict__ xs2,
    const float* __restrict__ xb1, const float* __restrict__ xb2,
    const float* __restrict__ att_w, const float* __restrict__ att_b,
    float* __restrict__ sc)
{
    const int lane = threadIdx.x & 63;
    const int w = threadIdx.x >> 6;
    const int r = blockIdx.x * 4 + w;
    const int which = r >= NB * NN;
    const int rr = r - which * NB * NN;

    const float* p0 = which ? xs2 : x;
    const float* p1 = which ? xb1 : xs1;
    const float* p2 = which ? xb2 : xs2;

    size_t idx = (size_t)rr * NC + lane;
    float nf = (p0[idx] + p1[idx] + p2[idx]) * (1.0f / 3.0f);
    float v = nf * att_w[lane];
    #pragma unroll
    for (int off = 32; off > 0; off >>= 1) v += __shfl_xor(v, off);
    if (lane == 0) sc[r] = v + att_b[0];
}

// ======= Stage B: softmax over the 1024 nodes of one (which,b) =======
__global__ __launch_bounds__(256) void softmax_kernel(float* __restrict__ sc)
{
    const int wb = blockIdx.x;
    const int t = threadIdx.x;
    const int lane = t & 63;
    const int w = t >> 6;
    float* p = sc + (size_t)wb * NN;

    __shared__ float red[4];
    float4 v = reinterpret_cast<const float4*>(p)[t];
    float m = fmaxf(fmaxf(v.x, v.y), fmaxf(v.z, v.w));
    #pragma unroll
    for (int off = 32; off > 0; off >>= 1) m = fmaxf(m, __shfl_xor(m, off));
    if (lane == 0) red[w] = m;
    __syncthreads();
    m = fmaxf(fmaxf(red[0], red[1]), fmaxf(red[2], red[3]));
    __syncthreads();
    v.x = expf(v.x - m); v.y = expf(v.y - m); v.z = expf(v.z - m); v.w = expf(v.w - m);
    float s = v.x + v.y + v.z + v.w;
    #pragma unroll
    for (int off = 32; off > 0; off >>= 1) s += __shfl_xor(s, off);
    if (lane == 0) red[w] = s;
    __syncthreads();
    const float inv = 1.0f / (red[0] + red[1] + red[2] + red[3]);
    v.x *= inv; v.y *= inv; v.z *= inv; v.w *= inv;
    reinterpret_cast<float4*>(p)[t] = v;
}

// ======= Stage C: partial weighted sums over 64-node chunks =======
__global__ __launch_bounds__(256) void poolpart_kernel(
    const float* __restrict__ x, const float* __restrict__ xs1, const float* __restrict__ xs2,
    const float* __restrict__ xb1, const float* __restrict__ xb2,
    const float* __restrict__ sc, float* __restrict__ partial)
{
    const int chunk = blockIdx.x;
    const int b = blockIdx.y;
    const int which = blockIdx.z;
    const int lane = threadIdx.x & 63;
    const int w = threadIdx.x >> 6;

    const float* p0 = which ? xs2 : x;
    const float* p1 = which ? xb1 : xs1;
    const float* p2 = which ? xb2 : xs2;

    const int n0 = chunk * 64;
    const size_t base = (size_t)b * NN;
    float acc = 0.0f;
    for (int j = w; j < 64; j += 4) {
        int n = n0 + j;
        size_t idx = (base + n) * NC + lane;
        float nf = (p0[idx] + p1[idx] + p2[idx]) * (1.0f / 3.0f);
        acc += nf * sc[((size_t)which * NB + b) * NN + n];
    }
    __shared__ float red[4][64];
    red[w][lane] = acc;
    __syncthreads();
    if (w == 0) {
        float s = red[0][lane] + red[1][lane] + red[2][lane] + red[3][lane];
        partial[(((size_t)which * NB + b) * 16 + chunk) * 64 + lane] = s;
    }
}

// ======= Stage D: reduce partials + multiply by weights1 =======
__global__ __launch_bounds__(256) void poolfin_kernel(
    const float* __restrict__ partial, const float* __restrict__ w1,
    float* __restrict__ gf_out)
{
    const int wb = blockIdx.x;
    const int t = threadIdx.x;
    const int lane = t & 63;
    const int w = t >> 6;

    __shared__ float red[4][64];
    __shared__ float gfin[64];
    float acc = 0.0f;
    #pragma unroll
    for (int r = w; r < 16; r += 4)
        acc += partial[((size_t)wb * 16 + r) * 64 + lane];
    red[w][lane] = acc;
    __syncthreads();
    if (w == 0) gfin[lane] = red[0][lane] + red[1][lane] + red[2][lane] + red[3][lane];
    __syncthreads();
    if (w == 0) {
        float s = 0.0f;
        #pragma unroll
        for (int c = 0; c < 64; ++c) s += gfin[c] * w1[c * 64 + lane];
        gf_out[(size_t)wb * 64 + lane] = s;
    }
}

// ------- Kernel 4a: W[n][ki][o] = sum_e emb1[n,e] * pool[e][ki][o] (grid 192 x 4) -------
__global__ __launch_bounds__(256) void wbuild_kernel(
    const float* __restrict__ emb1, const float* __restrict__ pool,
    float* __restrict__ W)
{
    const int ki = blockIdx.x;            // 0..191
    const int chunk = blockIdx.y;         // 0..3
    const int t = threadIdx.x;
    const int o = t & 63;

    __shared__ float slab[16][64];
    __shared__ float eloc[256][16];

    for (int idx = t; idx < 1024; idx += 256)
        slab[idx >> 6][idx & 63] = pool[((size_t)(idx >> 6) * 192 + ki) * 64 + (idx & 63)];
    for (int idx = t; idx < 4096; idx += 256)
        eloc[idx >> 4][idx & 15] = emb1[((size_t)chunk * 256 + (idx >> 4)) * 16 + (idx & 15)];
    __syncthreads();
    for (int nl = t >> 6; nl < 256; nl += 4) {
        float s = 0.0f;
        #pragma unroll
        for (int e = 0; e < 16; ++e) s += eloc[nl][e] * slab[e][o];
        W[((size_t)(chunk * 256 + nl) * 192 + ki) * 64 + o] = s;
    }
}

// ------- Kernel 4b: per node n, out[b,o] (pass0: = a*d + bias + gf; pass1: += b*d) -------
__global__ __launch_bounds__(256) void apply_kernel(
    const float* __restrict__ W, const float* __restrict__ emb1,
    const float* __restrict__ bias_pool,
    const float* __restrict__ s0, const float* __restrict__ s1, const float* __restrict__ s2,
    const float* __restrict__ gf, const float* __restrict__ scale,
    float* __restrict__ out, int pass)
{
    const int n = blockIdx.x;
    const int t = threadIdx.x;
    const int o = t & 63;
    const int bg = t >> 6;

    __shared__ float Wn[192][64];
    __shared__ float Xs[3][32][64];
    __shared__ float e1s[16];

    if (t < 16) e1s[t] = emb1[n * 16 + t];
    {
        const float4* src = reinterpret_cast<const float4*>(W + (size_t)n * 192 * 64);
        float4* dst = reinterpret_cast<float4*>(&Wn[0][0]);
        #pragma unroll
        for (int r = 0; r < 12; ++r) dst[t + 256 * r] = src[t + 256 * r];
    }
    const float* srcs[3] = {s0, s1, s2};
    #pragma unroll
    for (int k = 0; k < 3; ++k) {
        const float* sp = srcs[k];
        #pragma unroll
        for (int r = 0; r < 2; ++r) {
            int idx = t + 256 * r;
            int b = idx >> 4, i4 = idx & 15;
            reinterpret_cast<float4*>(&Xs[k][b][0])[i4] =
                reinterpret_cast<const float4*>(sp + ((size_t)b * NN + n) * NC)[i4];
        }
    }
    __syncthreads();

    float acc[8] = {};
    #pragma unroll 4
    for (int ki = 0; ki < 192; ++ki) {
        float wv = Wn[ki][o];
        int k = ki >> 6, i = ki & 63;
        #pragma unroll
        for (int j = 0; j < 8; ++j) acc[j] += Xs[k][bg * 8 + j][i] * wv;
    }

    const float sc = scale[0];
    if (pass == 0) {
        float bias_o = 0.0f;
        #pragma unroll
        for (int e = 0; e < 16; ++e) bias_o += e1s[e] * bias_pool[e * 64 + o];
        #pragma unroll
        for (int j = 0; j < 8; ++j) {
            int b = bg * 8 + j;
            float g = gf[(size_t)b * 64 + o] + gf[((size_t)NB + b) * 64 + o];
            out[((size_t)b * NN + n) * NC + o] = sc * acc[j] + bias_o + g;
        }
    } else {
        #pragma unroll
        for (int j = 0; j < 8; ++j) {
            int b = bg * 8 + j;
            out[((size_t)b * NN + n) * NC + o] += sc * acc[j];
        }
    }
}

// ------- Fallback final kernel (ws too small) -------
__global__ __launch_bounds__(256) void final_kernel(
    const float* __restrict__ emb1,
    const float* __restrict__ wpf, const float* __restrict__ wpb,
    const float* __restrict__ bias_pool,
    const float* __restrict__ x, const float* __restrict__ xs1, const float* __restrict__ xs2,
    const float* __restrict__ xb1, const float* __restrict__ xb2,
    const float* __restrict__ gf, const float* __restrict__ alpha, const float* __restrict__ beta,
    float* __restrict__ out)
{
    const int n = blockIdx.x;
    const int t = threadIdx.x;
    const int o = t & 63;
    const int bg = t >> 6;

    __shared__ float Wk[64][64];
    __shared__ float xk[32][64];
    __shared__ float e1[16];
    if (t < 16) e1[t] = emb1[n * 16 + t];

    float acc[2][8];
    #pragma unroll
    for (int d = 0; d < 2; ++d)
        #pragma unroll
        for (int j = 0; j < 8; ++j) acc[d][j] = 0.0f;

    const float* srcs[2][3] = {{x, xs1, xs2}, {xs2, xb1, xb2}};

    #pragma unroll
    for (int dir = 0; dir < 2; ++dir) {
        const float* wp = dir ? wpb : wpf;
        #pragma unroll
        for (int k = 0; k < 3; ++k) {
            __syncthreads();
            for (int idx = t; idx < 4096; idx += 256) {
                int i = idx >> 6, oo = idx & 63;
                float s = 0.0f;
                #pragma unroll
                for (int e = 0; e < 16; ++e) s += e1[e] * wp[(((size_t)e * 3 + k) * 64 + i) * 64 + oo];
                Wk[i][oo] = s;
            }
            const float* src = srcs[dir][k];
            for (int idx = t; idx < 2048; idx += 256) {
                int bb = idx >> 6, ii = idx & 63;
                xk[bb][ii] = src[((size_t)bb * NN + n) * NC + ii];
            }
            __syncthreads();
            #pragma unroll
            for (int j = 0; j < 8; ++j) {
                int bb = bg * 8 + j;
                float s = 0.0f;
                #pragma unroll
                for (int i = 0; i < 64; i += 4) {
                    float4 xv = *reinterpret_cast<const float4*>(&xk[bb][i]);
                    s += xv.x * Wk[i][o] + xv.y * Wk[i + 1][o] + xv.z * Wk[i + 2][o] + xv.w * Wk[i + 3][o];
                }
                acc[dir][j] += s;
            }
        }
    }

    float bias_o = 0.0f;
    #pragma unroll
    for (int e = 0; e < 16; ++e) bias_o += e1[e] * bias_pool[e * 64 + o];
    const float al = alpha[0], be = beta[0];
    #pragma unroll
    for (int j = 0; j < 8; ++j) {
        int bb = bg * 8 + j;
        float g = gf[(size_t)bb * 64 + o] + gf[((size_t)NB + bb) * 64 + o];
        out[((size_t)bb * NN + n) * NC + o] = al * acc[0][j] + be * acc[1][j] + bias_o + g;
    }
}

// ------- Fallback attnpool (ws too small) -------
__global__ __launch_bounds__(256) void attnpool_kernel(
    const float* __restrict__ a0, const float* __restrict__ a1, const float* __restrict__ a2,
    const float* __restrict__ c0, const float* __restrict__ c1, const float* __restrict__ c2,
    const float* __restrict__ att_w, const float* __restrict__ att_b,
    const float* __restrict__ w1, float* __restrict__ gf_out)
{
    const int b = blockIdx.x;
    const int which = blockIdx.y;
    const float* p0 = which ? c0 : a0;
    const float* p1 = which ? c1 : a1;
    const float* p2 = which ? c2 : a2;
    const int t = threadIdx.x;
    const int lane = t & 63;
    const int w = t >> 6;

    __shared__ float sc[NN];
    __shared__ float red[4];
    __shared__ float gfp[4][64];
    __shared__ float gfin[64];

    const float aw = att_w[lane];
    const size_t base = (size_t)b * NN * NC;

    for (int n = w; n < NN; n += 4) {
        size_t idx = base + (size_t)n * NC + lane;
        float nf = (p0[idx] + p1[idx] + p2[idx]) * (1.0f / 3.0f);
        float v = nf * aw;
        #pragma unroll
        for (int off = 32; off > 0; off >>= 1) v += __shfl_xor(v, off);
        if (lane == 0) sc[n] = v + att_b[0];
    }
    __syncthreads();
    float m = -INFINITY;
    for (int i = t; i < NN; i += 256) m = fmaxf(m, sc[i]);
    #pragma unroll
    for (int off = 32; off > 0; off >>= 1) m = fmaxf(m, __shfl_xor(m, off));
    if (lane == 0) red[w] = m;
    __syncthreads();
    m = fmaxf(fmaxf(red[0], red[1]), fmaxf(red[2], red[3]));
    __syncthreads();
    float s = 0.0f;
    for (int i = t; i < NN; i += 256) { float e = expf(sc[i] - m); sc[i] = e; s += e; }
    #pragma unroll
    for (int off = 32; off > 0; off >>= 1) s += __shfl_xor(s, off);
    if (lane == 0) red[w] = s;
    __syncthreads();
    const float inv_denom = 1.0f / (red[0] + red[1] + red[2] + red[3]);

    float acc = 0.0f;
    for (int n = w; n < NN; n += 4) {
        size_t idx = base + (size_t)n * NC + lane;
        float nf = (p0[idx] + p1[idx] + p2[idx]) * (1.0f / 3.0f);
        acc += nf * sc[n];
    }
    gfp[w][lane] = acc;
    __syncthreads();
    if (w == 0) gfin[lane] = (gfp[0][lane] + gfp[1][lane] + gfp[2][lane] + gfp[3][lane]) * inv_denom;
    __syncthreads();
    if (w == 0) {
        float s2 = 0.0f;
        #pragma unroll
        for (int c = 0; c < 64; ++c) s2 += gfin[c] * w1[c * 64 + lane];
        gf_out[((size_t)which * NB + b) * 64 + lane] = s2;
    }
}

extern "C" void kernel_launch(void* const* d_in, const int* in_sizes, int n_in,
                              void* d_out, int out_size, void* d_ws, size_t ws_size,
                              hipStream_t stream)
{
    const float* x      = (const float*)d_in[0];
    const float* emb0   = (const float*)d_in[1];
    const float* emb1   = (const float*)d_in[2];
    const float* speed  = (const float*)d_in[5];
    const float* occupy = (const float*)d_in[6];
    const float* fw1 = (const float*)d_in[7];
    const float* fb1 = (const float*)d_in[8];
    const float* fw2 = (const float*)d_in[9];
    const float* fb2 = (const float*)d_in[10];
    const float* fw3 = (const float*)d_in[11];
    const float* fb3 = (const float*)d_in[12];
    const float* gw1 = (const float*)d_in[13];
    const float* gb1 = (const float*)d_in[14];
    const float* gw2 = (const float*)d_in[15];
    const float* gb2 = (const float*)d_in[16];
    const float* gw3 = (const float*)d_in[17];
    const float* gb3 = (const float*)d_in[18];
    const float* alpha = (const float*)d_in[19];
    const float* beta  = (const float*)d_in[20];
    const float* wpf = (const float*)d_in[21];
    const float* wpb = (const float*)d_in[22];
    const float* bias_pool = (const float*)d_in[23];
    const float* w1 = (const float*)d_in[24];
    const float* att_w = (const float*)d_in[25];
    const float* att_b = (const float*)d_in[26];
    float* out = (float*)d_out;

    float* ws = (float*)d_ws;
    float* nv  = ws;                                   // B*N*E
    float* xs1 = nv + (size_t)NB * NN * NE;            // B*N*C each
    float* xs2 = xs1 + (size_t)NB * NN * NC;
    float* xb1 = xs2 + (size_t)NB * NN * NC;
    float* xb2 = xb1 + (size_t)NB * NN * NC;
    float* gfb = xb2 + (size_t)NB * NN * NC;           // [2][B][64]
    float* scb = gfb + 4096;                           // [2][B][N]
    float* ppb = scb + (size_t)2 * NB * NN;            // [2][B][16][64]
    float* Wbuf = ppb + (size_t)2 * NB * 16 * 64;      // N*192*64
    f16* Sh = (f16*)(Wbuf + (size_t)NN * 192 * 64);    // B*N*N f16 planes
    f16* Sl = Sh + (size_t)NB * NN * NN;

    const size_t base_elems = (size_t)NB * NN * NE + 4 * (size_t)NB * NN * NC + 4096;
    const size_t attn_elems = (size_t)2 * NB * NN + (size_t)2 * NB * 16 * 64;
    const size_t w_elems = (size_t)NN * 192 * 64;
    const size_t need_mid = (base_elems + attn_elems + w_elems) * sizeof(float);
    const size_t need_full = need_mid + (size_t)2 * NB * NN * NN * sizeof(f16);

    hipLaunchKernelGGL(nv_kernel, dim3(NB * NN / 64), dim3(64), 0, stream,
                       x, emb0, speed, occupy, fw1, fb1, fw2, fb2, fw3, fb3,
                       gw1, gb1, gw2, gb2, gw3, gb3, nv);

    if (ws_size >= need_full) {
        hipLaunchKernelGGL(sgen_kernel, dim3(NB, NN / 128), dim3(256), 0, stream, nv, Sh, Sl);
        dim3 gd2(NB, NN / 64);
        hipLaunchKernelGGL(diffuse2_kernel, gd2, dim3(256), 0, stream, Sh, Sl, x, xs1);
        hipLaunchKernelGGL(diffuse2_kernel, gd2, dim3(256), 0, stream, Sh, Sl, xs1, xs2);
        hipLaunchKernelGGL(diffuse2_kernel, gd2, dim3(256), 0, stream, Sh, Sl, xs2, xb1);
        hipLaunchKernelGGL(diffuse2_kernel, gd2, dim3(256), 0, stream, Sh, Sl, xb1, xb2);
    } else {
        dim3 gd(NB, NN / 128);
        hipLaunchKernelGGL(diffuse_mfma_kernel, gd, dim3(256), 0, stream, nv, x, xs1);
        hipLaunchKernelGGL(diffuse_mfma_kernel, gd, dim3(256), 0, stream, nv, xs1, xs2);
        hipLaunchKernelGGL(diffuse_mfma_kernel, gd, dim3(256), 0, stream, nv, xs2, xb1);
        hipLaunchKernelGGL(diffuse_mfma_kernel, gd, dim3(256), 0, stream, nv, xb1, xb2);
    }

    if (ws_size >= need_mid) {
        hipLaunchKernelGGL(scores_kernel, dim3(2 * NB * NN / 4), dim3(256), 0, stream,
                           x, xs1, xs2, xb1, xb2, att_w, att_b, scb);
        hipLaunchKernelGGL(softmax_kernel, dim3(2 * NB), dim3(256), 0, stream, scb);
        hipLaunchKernelGGL(poolpart_kernel, dim3(16, NB, 2), dim3(256), 0, stream,
                           x, xs1, xs2, xb1, xb2, scb, ppb);
        hipLaunchKernelGGL(poolfin_kernel, dim3(2 * NB), dim3(256), 0, stream, ppb, w1, gfb);
        hipLaunchKernelGGL(wbuild_kernel, dim3(192, 4), dim3(256), 0, stream, emb1, wpf, Wbuf);
        hipLaunchKernelGGL(apply_kernel, dim3(NN), dim3(256), 0, stream,
                           Wbuf, emb1, bias_pool, x, xs1, xs2, gfb, alpha, out, 0);
        hipLaunchKernelGGL(wbuild_kernel, dim3(192, 4), dim3(256), 0, stream, emb1, wpb, Wbuf);
        hipLaunchKernelGGL(apply_kernel, dim3(NN), dim3(256), 0, stream,
                           Wbuf, emb1, bias_pool, xs2, xb1, xb2, gfb, beta, out, 1);
    } else {
        hipLaunchKernelGGL(attnpool_kernel, dim3(NB, 2), dim3(256), 0, stream,
                           x, xs1, xs2, xs2, xb1, xb2, att_w, att_b, w1, gfb);
        hipLaunchKernelGGL(final_kernel, dim3(NN), dim3(256), 0, stream,
                           emb1, wpf, wpb, bias_pool, x, xs1, xs2, xb1, xb2, gfb, alpha, beta, out);
    }
}